// Round 1
// baseline (557.641 us; speedup 1.0000x reference)
//
#include <hip/hip_runtime.h>
#include <hip/hip_bf16.h>

// Problem constants
#define Bq 32
#define Lq 256
#define Hq 8
#define Eq 16
#define Nn (Bq*Hq)        // 256 sequences
#define T 254             // Lq - 3 + 1
#define C1 64             // conv1 out channels
#define C2 128            // conv2 out channels
#define A 145             // E + 1 + 128 augmented channels
#define SIG_CH (A + A*A)  // 21170
#define OUT 256

// ---------------------------------------------------------------------------
// Kernel A: conv1(k=3,16->64) -> conv2(k=1,64->128)+ReLU -> aug[n][t][145]
// aug channels: 0..15 = x[n,t+2,:], 16 = t/253, 17..144 = relu(conv2)
// grid: (8 t-tiles of 32, 256 n), 256 threads
// ---------------------------------------------------------------------------
__global__ __launch_bounds__(256) void aug_kernel(
    const float* __restrict__ q,
    const float* __restrict__ w1, const float* __restrict__ b1,
    const float* __restrict__ w2, const float* __restrict__ b2,
    float* __restrict__ aug)
{
    __shared__ __align__(16) float w1s[3*16*64];   // 3072
    __shared__ __align__(16) float b1s[64];
    __shared__ __align__(16) float w2s[64*128];    // 8192
    __shared__ __align__(16) float b2s[128];
    __shared__ __align__(16) float xs[34*16];      // x rows t0..t0+33
    __shared__ __align__(16) float a1s[32*64];     // conv1 outputs for this tile

    const int tid = threadIdx.x;
    const int n  = blockIdx.y;
    const int b  = n >> 3, h = n & 7;
    const int t0 = blockIdx.x * 32;

    for (int i = tid; i < 3072; i += 256) w1s[i] = w1[i];
    if (tid < 64)  b1s[tid] = b1[tid];
    for (int i = tid; i < 8192; i += 256) w2s[i] = w2[i];
    if (tid < 128) b2s[tid] = b2[tid];
    for (int i = tid; i < 34*16; i += 256) {
        int row = i >> 4, ch = i & 15;
        int t = t0 + row;
        xs[i] = (t < Lq) ? q[(((b*Lq + t)*Hq + h) << 4) + ch] : 0.f;
    }
    __syncthreads();

    // conv1: a1[tt][c], 32*64 outputs, 8 per thread
    #pragma unroll
    for (int p = 0; p < 8; ++p) {
        int idx = tid + p*256;
        int c = idx & 63, tt = idx >> 6;
        float s = b1s[c];
        #pragma unroll
        for (int k = 0; k < 3; ++k)
            #pragma unroll
            for (int i = 0; i < 16; ++i)
                s += xs[(tt+k)*16 + i] * w1s[((k*16 + i) << 6) + c];
        a1s[idx] = s;
    }
    __syncthreads();

    // aug: 32*145 outputs
    const float inv253 = 1.0f / 253.0f;
    for (int idx = tid; idx < 32*A; idx += 256) {
        int tt = idx / A;
        int ch = idx - tt*A;
        int t = t0 + tt;
        if (t >= T) continue;
        float val;
        if (ch < 16) {
            val = xs[(tt+2)*16 + ch];
        } else if (ch == 16) {
            val = (float)t * inv253;
        } else {
            int c = ch - 17;
            float s = b2s[c];
            #pragma unroll 8
            for (int i = 0; i < 64; ++i)
                s += a1s[tt*64 + i] * w2s[(i << 7) + c];
            val = fmaxf(s, 0.f);
        }
        aug[((long)n*T + t)*A + ch] = val;
    }
}

// ---------------------------------------------------------------------------
// Kernel B: depth-2 signature per n.
// s1 = aug[T-1]-aug[0]; s2[i,j] = sum_t (0.5*(aug_t+aug_{t+1}) - aug_0)_i * d_t[j]
// One block per n, 256 threads; each thread owns up to 6 4x4 register tiles of
// the (padded 148x148) s2 matrix.
// ---------------------------------------------------------------------------
#define PADA 148
#define NT 37           // 148/4 tiles per dim
#define NTILES (NT*NT)  // 1369

__global__ __launch_bounds__(256) void sig_kernel(
    const float* __restrict__ aug, float* __restrict__ sig)
{
    const int tid = threadIdx.x;
    const int n = blockIdx.x;
    const float* an = aug + (long)n*T*A;

    __shared__ __align__(16) float a0[PADA];
    __shared__ __align__(16) float mm[PADA];
    __shared__ __align__(16) float dd[PADA];

    if (tid < PADA) a0[tid] = (tid < A) ? an[tid] : 0.f;

    int ti[6], tj[6];
    bool tv[6];
    #pragma unroll
    for (int s = 0; s < 6; ++s) {
        int tile = tid + s*256;
        tv[s] = (tile < NTILES);
        int tt = tv[s] ? tile : 0;
        ti[s] = tt / NT;
        tj[s] = tt - ti[s]*NT;
    }
    float acc[6][16];
    #pragma unroll
    for (int s = 0; s < 6; ++s)
        #pragma unroll
        for (int e = 0; e < 16; ++e) acc[s][e] = 0.f;

    __syncthreads();

    for (int t = 0; t < T-1; ++t) {
        if (tid < PADA) {
            float c0 = (tid < A) ? an[t*A + tid]     : 0.f;
            float c1 = (tid < A) ? an[(t+1)*A + tid] : 0.f;
            dd[tid] = c1 - c0;
            mm[tid] = 0.5f*(c0 + c1) - a0[tid];
        }
        __syncthreads();
        #pragma unroll
        for (int s = 0; s < 6; ++s) {
            if (!tv[s]) continue;
            float4 mv = *(const float4*)(mm + (ti[s] << 2));
            float4 dv = *(const float4*)(dd + (tj[s] << 2));
            float* a = acc[s];
            a[0]  += mv.x*dv.x; a[1]  += mv.x*dv.y; a[2]  += mv.x*dv.z; a[3]  += mv.x*dv.w;
            a[4]  += mv.y*dv.x; a[5]  += mv.y*dv.y; a[6]  += mv.y*dv.z; a[7]  += mv.y*dv.w;
            a[8]  += mv.z*dv.x; a[9]  += mv.z*dv.y; a[10] += mv.z*dv.z; a[11] += mv.z*dv.w;
            a[12] += mv.w*dv.x; a[13] += mv.w*dv.y; a[14] += mv.w*dv.z; a[15] += mv.w*dv.w;
        }
        __syncthreads();
    }

    float* sn = sig + (long)n*SIG_CH;
    if (tid < A) sn[tid] = an[(T-1)*A + tid] - a0[tid];
    #pragma unroll
    for (int s = 0; s < 6; ++s) {
        if (!tv[s]) continue;
        #pragma unroll
        for (int r = 0; r < 4; ++r) {
            int i = (ti[s] << 2) + r;
            if (i >= A) continue;
            #pragma unroll
            for (int c = 0; c < 4; ++c) {
                int j = (tj[s] << 2) + c;
                if (j < A) sn[A + i*A + j] = acc[s][r*4 + c];
            }
        }
    }
}

// ---------------------------------------------------------------------------
// out init: out[n][o] = lin_b[o]
// ---------------------------------------------------------------------------
__global__ __launch_bounds__(256) void init_out_kernel(
    const float* __restrict__ lb, float* __restrict__ out)
{
    out[blockIdx.x * OUT + threadIdx.x] = lb[threadIdx.x];
}

// ---------------------------------------------------------------------------
// Kernel C: out += sig(256x21170) @ W(21170x256), 64x64 tiles, split-K=16,
// fp32 atomicAdd epilogue.
// grid: (4 o-tiles, 4 n-tiles, 16 k-chunks), 256 threads (16x16, 4x4 micro)
// ---------------------------------------------------------------------------
#define BK 16
#define KCHUNK 1324   // ceil(21170/16)

__global__ __launch_bounds__(256) void gemm_kernel(
    const float* __restrict__ sig, const float* __restrict__ W,
    float* __restrict__ out)
{
    __shared__ __align__(16) float As[64][17];   // [n][k], padded
    __shared__ __align__(16) float Bs[BK][64];   // [k][o]

    const int tid = threadIdx.x;
    const int tx = tid & 15, ty = tid >> 4;
    const int o0 = blockIdx.x * 64;
    const int n0 = blockIdx.y * 64;
    const int k0 = blockIdx.z * KCHUNK;
    const int kend = min(k0 + KCHUNK, SIG_CH);

    float acc[16];
    #pragma unroll
    for (int e = 0; e < 16; ++e) acc[e] = 0.f;

    for (int k = k0; k < kend; k += BK) {
        int klen = kend - k; if (klen > BK) klen = BK;
        #pragma unroll
        for (int p = 0; p < 4; ++p) {
            int idx = tid + p*256;
            int kk = idx & 15, nn = idx >> 4;
            As[nn][kk] = (kk < klen) ? sig[(long)(n0+nn)*SIG_CH + k + kk] : 0.f;
        }
        #pragma unroll
        for (int p = 0; p < 4; ++p) {
            int idx = tid + p*256;
            int oo = idx & 63, kk = idx >> 6;
            Bs[kk][oo] = (kk < klen) ? W[(long)(k+kk)*OUT + o0 + oo] : 0.f;
        }
        __syncthreads();
        #pragma unroll
        for (int kk = 0; kk < BK; ++kk) {
            float a0 = As[(ty<<2)+0][kk];
            float a1 = As[(ty<<2)+1][kk];
            float a2 = As[(ty<<2)+2][kk];
            float a3 = As[(ty<<2)+3][kk];
            float4 bv = *(const float4*)(&Bs[kk][tx<<2]);
            acc[0]  += a0*bv.x; acc[1]  += a0*bv.y; acc[2]  += a0*bv.z; acc[3]  += a0*bv.w;
            acc[4]  += a1*bv.x; acc[5]  += a1*bv.y; acc[6]  += a1*bv.z; acc[7]  += a1*bv.w;
            acc[8]  += a2*bv.x; acc[9]  += a2*bv.y; acc[10] += a2*bv.z; acc[11] += a2*bv.w;
            acc[12] += a3*bv.x; acc[13] += a3*bv.y; acc[14] += a3*bv.z; acc[15] += a3*bv.w;
        }
        __syncthreads();
    }

    #pragma unroll
    for (int r = 0; r < 4; ++r)
        #pragma unroll
        for (int c = 0; c < 4; ++c)
            atomicAdd(&out[(n0 + (ty<<2) + r)*OUT + o0 + (tx<<2) + c], acc[r*4 + c]);
}

// ---------------------------------------------------------------------------
extern "C" void kernel_launch(void* const* d_in, const int* in_sizes, int n_in,
                              void* d_out, int out_size, void* d_ws, size_t ws_size,
                              hipStream_t stream) {
    const float* q  = (const float*)d_in[0];
    // d_in[1] = k, d_in[2] = v, d_in[3] = mask  -- unused by the reference
    const float* w1 = (const float*)d_in[4];
    const float* b1 = (const float*)d_in[5];
    const float* w2 = (const float*)d_in[6];
    const float* b2 = (const float*)d_in[7];
    const float* lw = (const float*)d_in[8];
    const float* lb = (const float*)d_in[9];
    float* out = (float*)d_out;

    // workspace layout: aug[256*254*145] fp32 (37.7MB) | sig[256*21170] fp32 (21.7MB)
    float* aug = (float*)d_ws;
    float* sig = (float*)((char*)d_ws + (size_t)Nn*T*A*sizeof(float));

    aug_kernel<<<dim3(8, Nn), 256, 0, stream>>>(q, w1, b1, w2, b2, aug);
    sig_kernel<<<Nn, 256, 0, stream>>>(aug, sig);
    init_out_kernel<<<Nn, 256, 0, stream>>>(lb, out);
    gemm_kernel<<<dim3(4, 4, 16), 256, 0, stream>>>(sig, lw, out);
}

// Round 2
// 446.634 us; speedup vs baseline: 1.2485x; 1.2485x over previous
//
#include <hip/hip_runtime.h>
#include <hip/hip_bf16.h>

// Problem constants
#define Bq 32
#define Lq 256
#define Hq 8
#define Eq 16
#define Nn (Bq*Hq)        // 256 sequences
#define T 254             // Lq - 3 + 1
#define A 145             // E + 1 + 128 augmented channels
#define SIG_CH (A + A*A)  // 21170
#define OUT 256

// ---------------------------------------------------------------------------
// Kernel A: conv1(k=3,16->64) -> conv2(k=1,64->128)+ReLU -> aug[n][t][145]
// ---------------------------------------------------------------------------
__global__ __launch_bounds__(256) void aug_kernel(
    const float* __restrict__ q,
    const float* __restrict__ w1, const float* __restrict__ b1,
    const float* __restrict__ w2, const float* __restrict__ b2,
    float* __restrict__ aug)
{
    __shared__ __align__(16) float w1s[3*16*64];
    __shared__ __align__(16) float b1s[64];
    __shared__ __align__(16) float w2s[64*128];
    __shared__ __align__(16) float b2s[128];
    __shared__ __align__(16) float xs[34*16];
    __shared__ __align__(16) float a1s[32*64];

    const int tid = threadIdx.x;
    const int n  = blockIdx.y;
    const int b  = n >> 3, h = n & 7;
    const int t0 = blockIdx.x * 32;

    for (int i = tid; i < 3072; i += 256) w1s[i] = w1[i];
    if (tid < 64)  b1s[tid] = b1[tid];
    for (int i = tid; i < 8192; i += 256) w2s[i] = w2[i];
    if (tid < 128) b2s[tid] = b2[tid];
    for (int i = tid; i < 34*16; i += 256) {
        int row = i >> 4, ch = i & 15;
        int t = t0 + row;
        xs[i] = (t < Lq) ? q[(((b*Lq + t)*Hq + h) << 4) + ch] : 0.f;
    }
    __syncthreads();

    #pragma unroll
    for (int p = 0; p < 8; ++p) {
        int idx = tid + p*256;
        int c = idx & 63, tt = idx >> 6;
        float s = b1s[c];
        #pragma unroll
        for (int k = 0; k < 3; ++k)
            #pragma unroll
            for (int i = 0; i < 16; ++i)
                s += xs[(tt+k)*16 + i] * w1s[((k*16 + i) << 6) + c];
        a1s[idx] = s;
    }
    __syncthreads();

    const float inv253 = 1.0f / 253.0f;
    for (int idx = tid; idx < 32*A; idx += 256) {
        int tt = idx / A;
        int ch = idx - tt*A;
        int t = t0 + tt;
        if (t >= T) continue;
        float val;
        if (ch < 16) {
            val = xs[(tt+2)*16 + ch];
        } else if (ch == 16) {
            val = (float)t * inv253;
        } else {
            int c = ch - 17;
            float s = b2s[c];
            #pragma unroll 8
            for (int i = 0; i < 64; ++i)
                s += a1s[tt*64 + i] * w2s[(i << 7) + c];
            val = fmaxf(s, 0.f);
        }
        aug[((long)n*T + t)*A + ch] = val;
    }
}

// ---------------------------------------------------------------------------
// Kernel B: depth-2 signature per n, lower-triangle only + Chen mirror.
// s1 = aug[T-1]-aug[0]
// s2[i,j] = sum_t m_t[i]*d_t[j],  m_t = 0.5*(aug_t+aug_{t+1}) - aug_0
// Chen: s2[i,j] = s1[i]*s1[j] - s2[j,i]  -> compute tiles with r>=c only.
// 256 threads, 8x8 register tiles over padded 152x152, t chunked by 8.
// ---------------------------------------------------------------------------
#define PADA 152
#define NTRI 190      // 19*20/2 lower-triangle 8x8 tiles
#define TCH 8

__global__ __launch_bounds__(256) void sig_kernel(
    const float* __restrict__ aug, float* __restrict__ sig)
{
    const int tid = threadIdx.x;
    const int n = blockIdx.x;
    const float* an = aug + (long)n*T*A;

    __shared__ __align__(16) float a0s[PADA];
    __shared__ __align__(16) float s1s[PADA];
    __shared__ __align__(16) float rows[TCH+1][PADA];
    __shared__ __align__(16) float mm[TCH][PADA];
    __shared__ __align__(16) float dd[TCH][PADA];

    if (tid < PADA) {
        float a0 = (tid < A) ? an[tid] : 0.f;
        a0s[tid] = a0;
        s1s[tid] = ((tid < A) ? an[(T-1)*A + tid] : 0.f) - a0;
    }

    // triangle tile coords for tid < NTRI: (r,c) with c <= r, r < 19
    int r = 0, base = 0;
    const bool act = tid < NTRI;
    if (act) { while (base + r + 1 <= tid) { base += r + 1; ++r; } }
    const int c = tid - base;
    const int r0 = r*8, c0 = c*8;

    float acc[8][8];
    #pragma unroll
    for (int i = 0; i < 8; ++i)
        #pragma unroll
        for (int j = 0; j < 8; ++j) acc[i][j] = 0.f;

    __syncthreads();

    for (int t0 = 0; t0 < T-1; t0 += TCH) {
        // stage rows t0..t0+8 (clamped; clamp => d=0 for tail, harmless)
        for (int i = tid; i < (TCH+1)*PADA; i += 256) {
            int rr = i / PADA, ch = i - rr*PADA;
            int t = t0 + rr; if (t > T-1) t = T-1;
            rows[rr][ch] = (ch < A) ? an[t*A + ch] : 0.f;
        }
        __syncthreads();
        for (int i = tid; i < TCH*PADA; i += 256) {
            int tt = i / PADA, ch = i - tt*PADA;
            float x0 = rows[tt][ch], x1 = rows[tt+1][ch];
            dd[tt][ch] = x1 - x0;
            mm[tt][ch] = 0.5f*(x0 + x1) - a0s[ch];
        }
        __syncthreads();
        if (act) {
            #pragma unroll
            for (int tt = 0; tt < TCH; ++tt) {
                float4 m0 = *(const float4*)&mm[tt][r0];
                float4 m1 = *(const float4*)&mm[tt][r0+4];
                float4 d0 = *(const float4*)&dd[tt][c0];
                float4 d1 = *(const float4*)&dd[tt][c0+4];
                float mv[8] = {m0.x,m0.y,m0.z,m0.w,m1.x,m1.y,m1.z,m1.w};
                float dv[8] = {d0.x,d0.y,d0.z,d0.w,d1.x,d1.y,d1.z,d1.w};
                #pragma unroll
                for (int rr = 0; rr < 8; ++rr)
                    #pragma unroll
                    for (int cc = 0; cc < 8; ++cc)
                        acc[rr][cc] += mv[rr]*dv[cc];
            }
        }
        __syncthreads();
    }

    float* sn = sig + (long)n*SIG_CH;
    if (tid < A) sn[tid] = s1s[tid];
    if (act) {
        if (r == c) {
            // diagonal tile: full 8x8 computed directly
            #pragma unroll
            for (int rr = 0; rr < 8; ++rr) {
                int i = r0 + rr;
                if (i >= A) continue;
                #pragma unroll
                for (int cc = 0; cc < 8; ++cc) {
                    int j = c0 + cc;
                    if (j < A) sn[A + i*A + j] = acc[rr][cc];
                }
            }
        } else {
            // strictly-lower tile: write direct + Chen mirror
            #pragma unroll
            for (int rr = 0; rr < 8; ++rr) {
                int i = r0 + rr;
                if (i >= A) continue;
                #pragma unroll
                for (int cc = 0; cc < 8; ++cc) {
                    int j = c0 + cc;   // j <= 143 < A always for c < r
                    float v = acc[rr][cc];
                    sn[A + i*A + j] = v;
                    sn[A + j*A + i] = s1s[j]*s1s[i] - v;
                }
            }
        }
    }
}

// ---------------------------------------------------------------------------
// Kernel C: split-K GEMM, fp32: part[z] = sig[128 rows]x[W 128 cols] chunk
// 128x128 tile, 8x8 micro split as 4+4 halves (2-way LDS aliasing = free).
// grid (2,2,SPLITK), 256 threads.
// ---------------------------------------------------------------------------
#define GBK 16
#define SPLITK 128
#define KCHUNK 166   // ceil(21170/128)

__global__ __launch_bounds__(256) void gemm_kernel(
    const float* __restrict__ sig, const float* __restrict__ W,
    float* __restrict__ part)
{
    __shared__ __align__(16) float As[GBK][136];  // [kk][nn], pad 8
    __shared__ __align__(16) float Bs[GBK][128];  // [kk][oo]

    const int tid = threadIdx.x;
    const int tx = tid & 15, ty = tid >> 4;
    const int o0 = blockIdx.x * 128;
    const int n0 = blockIdx.y * 128;
    const int z  = blockIdx.z;
    const int k0 = z * KCHUNK;
    const int kend = min(k0 + KCHUNK, SIG_CH);

    float acc[8][8];
    #pragma unroll
    for (int i = 0; i < 8; ++i)
        #pragma unroll
        for (int j = 0; j < 8; ++j) acc[i][j] = 0.f;

    for (int k = k0; k < kend; k += GBK) {
        #pragma unroll
        for (int p = 0; p < 8; ++p) {
            int idx = tid + p*256;
            int nn = idx >> 4, kk = idx & 15;
            As[kk][nn] = (k + kk < kend) ? sig[(long)(n0+nn)*SIG_CH + k + kk] : 0.f;
            int oo = idx & 127, k2 = idx >> 7;
            Bs[k2][oo] = (k + k2 < kend) ? W[(long)(k+k2)*OUT + o0 + oo] : 0.f;
        }
        __syncthreads();
        #pragma unroll
        for (int kk = 0; kk < GBK; ++kk) {
            float4 a0 = *(const float4*)&As[kk][ty*4];
            float4 a1 = *(const float4*)&As[kk][64 + ty*4];
            float4 b0 = *(const float4*)&Bs[kk][tx*4];
            float4 b1 = *(const float4*)&Bs[kk][64 + tx*4];
            float av[8] = {a0.x,a0.y,a0.z,a0.w,a1.x,a1.y,a1.z,a1.w};
            float bv[8] = {b0.x,b0.y,b0.z,b0.w,b1.x,b1.y,b1.z,b1.w};
            #pragma unroll
            for (int rr = 0; rr < 8; ++rr)
                #pragma unroll
                for (int cc = 0; cc < 8; ++cc)
                    acc[rr][cc] += av[rr]*bv[cc];
        }
        __syncthreads();
    }

    float* pz = part + (long)z * (256*256);
    #pragma unroll
    for (int rh = 0; rh < 2; ++rh)
        #pragma unroll
        for (int rr = 0; rr < 4; ++rr) {
            int row = n0 + rh*64 + ty*4 + rr;
            int ar = rh*4 + rr;
            float4 v0 = {acc[ar][0], acc[ar][1], acc[ar][2], acc[ar][3]};
            float4 v1 = {acc[ar][4], acc[ar][5], acc[ar][6], acc[ar][7]};
            *(float4*)&pz[row*OUT + o0 + tx*4]      = v0;
            *(float4*)&pz[row*OUT + o0 + 64 + tx*4] = v1;
        }
}

// ---------------------------------------------------------------------------
// Kernel D: out[n][o] = lin_b[o] + sum_z part[z][n][o]
// ---------------------------------------------------------------------------
__global__ __launch_bounds__(256) void reduce_kernel(
    const float* __restrict__ part, const float* __restrict__ lb,
    float* __restrict__ out)
{
    int idx = blockIdx.x * 256 + threadIdx.x;
    float s = lb[idx & 255];
    #pragma unroll 8
    for (int z = 0; z < SPLITK; ++z)
        s += part[(long)z * (256*256) + idx];
    out[idx] = s;
}

// ---------------------------------------------------------------------------
extern "C" void kernel_launch(void* const* d_in, const int* in_sizes, int n_in,
                              void* d_out, int out_size, void* d_ws, size_t ws_size,
                              hipStream_t stream) {
    const float* q  = (const float*)d_in[0];
    const float* w1 = (const float*)d_in[4];
    const float* b1 = (const float*)d_in[5];
    const float* w2 = (const float*)d_in[6];
    const float* b2 = (const float*)d_in[7];
    const float* lw = (const float*)d_in[8];
    const float* lb = (const float*)d_in[9];
    float* out = (float*)d_out;

    // ws layout: [0: aug fp32 37.7MB, later reused as part 33.6MB][sig fp32 21.7MB]
    float* aug  = (float*)d_ws;
    float* part = (float*)d_ws;   // aliases aug (dead after sig_kernel)
    float* sig  = (float*)((char*)d_ws + (size_t)Nn*T*A*sizeof(float));

    aug_kernel<<<dim3(8, Nn), 256, 0, stream>>>(q, w1, b1, w2, b2, aug);
    sig_kernel<<<Nn, 256, 0, stream>>>(aug, sig);
    gemm_kernel<<<dim3(2, 2, SPLITK), 256, 0, stream>>>(sig, lw, part);
    reduce_kernel<<<(Nn*OUT)/256, 256, 0, stream>>>(part, lb, out);
}

// Round 3
// 330.296 us; speedup vs baseline: 1.6883x; 1.3522x over previous
//
#include <hip/hip_runtime.h>
#include <hip/hip_bf16.h>

// Problem constants
#define Bq 32
#define Lq 256
#define Hq 8
#define Eq 16
#define Nn (Bq*Hq)        // 256 sequences
#define T 254             // Lq - 3 + 1
#define A 145             // E + 1 + 128 augmented channels
#define SIG_CH (A + A*A)  // 21170
#define SIGP 21172        // padded row stride (mult of 4 -> 16B-aligned rows)
#define OUT 256

// ---------------------------------------------------------------------------
// Kernel A: one block per sequence n. Weights staged once. Full x in LDS.
// conv1(k=3,16->64) -> conv2(k=1,64->128)+ReLU -> aug[n][t][145]
// ---------------------------------------------------------------------------
__global__ __launch_bounds__(256) void aug_kernel(
    const float* __restrict__ q,
    const float* __restrict__ w1, const float* __restrict__ b1,
    const float* __restrict__ w2, const float* __restrict__ b2,
    float* __restrict__ aug)
{
    __shared__ __align__(16) float w1s[48*64];    // [j=k*16+i][c] 12KB
    __shared__ __align__(16) float w2s[64*128];   // [i][c] 32KB
    __shared__ __align__(16) float b1s[64];
    __shared__ __align__(16) float b2s[128];
    __shared__ __align__(16) float xs[256*16];    // full sequence 16KB
    __shared__ __align__(16) float a1s[32*64];    // conv1 chunk [tt][c] 8KB

    const int tid = threadIdx.x;
    const int n = blockIdx.x;
    const int b = n >> 3, h = n & 7;

    for (int i = tid; i < 48*64; i += 256) w1s[i] = w1[i];
    for (int i = tid; i < 64*128; i += 256) w2s[i] = w2[i];
    if (tid < 64)  b1s[tid] = b1[tid];
    if (tid < 128) b2s[tid] = b2[tid];
    // x: q[b][t][h][e] -> xs[t][e], float4
    {
        const float4* q4 = (const float4*)q + ((long)(b*Lq)*Hq + h)*4;  // + t*32 + e4
        float4* xs4 = (float4*)xs;
        #pragma unroll
        for (int p = 0; p < 4; ++p) {
            int idx = tid + p*256;
            int t = idx >> 2, e4 = idx & 3;
            xs4[idx] = q4[t*32 + e4];
        }
    }
    __syncthreads();

    const float inv253 = 1.0f / 253.0f;

    for (int t0 = 0; t0 < T; t0 += 32) {
        // ---- conv1: thread -> (c quad = 4*(tid&15), tt in {tid>>4, (tid>>4)+16})
        {
            const int c = (tid & 15) * 4;
            const int tg = tid >> 4;
            const int ta = t0 + tg, tb = t0 + tg + 16;
            float4 bb = *(const float4*)&b1s[c];
            float4 acc0 = bb, acc1 = bb;
            #pragma unroll
            for (int j = 0; j < 48; ++j) {
                const int dt = j >> 4, i = j & 15;
                float4 w = *(const float4*)&w1s[j*64 + c];
                int ra = ta + dt; if (ra > 255) ra = 255;   // clamp (masked later)
                int rb = tb + dt; if (rb > 255) rb = 255;
                float xa = xs[ra*16 + i];
                float xb = xs[rb*16 + i];
                acc0.x += xa*w.x; acc0.y += xa*w.y; acc0.z += xa*w.z; acc0.w += xa*w.w;
                acc1.x += xb*w.x; acc1.y += xb*w.y; acc1.z += xb*w.z; acc1.w += xb*w.w;
            }
            *(float4*)&a1s[tg*64 + c]      = acc0;
            *(float4*)&a1s[(tg+16)*64 + c] = acc1;
        }
        __syncthreads();

        // ---- conv2 + ReLU + store: thread -> (c quad = 4*(tid&31), tt = (tid>>5)+8j)
        {
            const int cq = (tid & 31) * 4;
            const int tg2 = tid >> 5;
            float4 bb = *(const float4*)&b2s[cq];
            float4 acc[4] = {bb, bb, bb, bb};
            #pragma unroll 16
            for (int i = 0; i < 64; ++i) {
                float4 w = *(const float4*)&w2s[i*128 + cq];
                #pragma unroll
                for (int j = 0; j < 4; ++j) {
                    float a = a1s[(tg2 + 8*j)*64 + i];
                    acc[j].x += a*w.x; acc[j].y += a*w.y; acc[j].z += a*w.z; acc[j].w += a*w.w;
                }
            }
            #pragma unroll
            for (int j = 0; j < 4; ++j) {
                int t = t0 + tg2 + 8*j;
                if (t < T) {
                    float* dst = aug + ((long)n*T + t)*A + 17 + cq;
                    dst[0] = fmaxf(acc[j].x, 0.f);
                    dst[1] = fmaxf(acc[j].y, 0.f);
                    dst[2] = fmaxf(acc[j].z, 0.f);
                    dst[3] = fmaxf(acc[j].w, 0.f);
                }
            }
        }

        // ---- channels 0..16 (trunc x + time)
        for (int idx = tid; idx < 17*32; idx += 256) {
            int ch = idx >> 5, tt = idx & 31;
            int t = t0 + tt;
            if (t < T) {
                float val = (ch < 16) ? xs[(t+2)*16 + ch] : (float)t * inv253;
                aug[((long)n*T + t)*A + ch] = val;
            }
        }
        __syncthreads();   // protect a1s before next chunk's conv1 writes
    }
}

// ---------------------------------------------------------------------------
// Kernel B: depth-2 signature per n, lower-triangle + Chen mirror.
// sig rows padded to SIGP (pads zeroed here).
// ---------------------------------------------------------------------------
#define PADA 152
#define NTRI 190
#define TCH 8

__global__ __launch_bounds__(256) void sig_kernel(
    const float* __restrict__ aug, float* __restrict__ sig)
{
    const int tid = threadIdx.x;
    const int n = blockIdx.x;
    const float* an = aug + (long)n*T*A;

    __shared__ __align__(16) float a0s[PADA];
    __shared__ __align__(16) float s1s[PADA];
    __shared__ __align__(16) float rows[TCH+1][PADA];
    __shared__ __align__(16) float mm[TCH][PADA];
    __shared__ __align__(16) float dd[TCH][PADA];

    if (tid < PADA) {
        float a0 = (tid < A) ? an[tid] : 0.f;
        a0s[tid] = a0;
        s1s[tid] = ((tid < A) ? an[(T-1)*A + tid] : 0.f) - a0;
    }

    int r = 0, base = 0;
    const bool act = tid < NTRI;
    if (act) { while (base + r + 1 <= tid) { base += r + 1; ++r; } }
    const int c = tid - base;
    const int r0 = r*8, c0 = c*8;

    float acc[8][8];
    #pragma unroll
    for (int i = 0; i < 8; ++i)
        #pragma unroll
        for (int j = 0; j < 8; ++j) acc[i][j] = 0.f;

    __syncthreads();

    for (int t0 = 0; t0 < T-1; t0 += TCH) {
        for (int i = tid; i < (TCH+1)*PADA; i += 256) {
            int rr = i / PADA, ch = i - rr*PADA;
            int t = t0 + rr; if (t > T-1) t = T-1;
            rows[rr][ch] = (ch < A) ? an[t*A + ch] : 0.f;
        }
        __syncthreads();
        for (int i = tid; i < TCH*PADA; i += 256) {
            int tt = i / PADA, ch = i - tt*PADA;
            float x0 = rows[tt][ch], x1 = rows[tt+1][ch];
            dd[tt][ch] = x1 - x0;
            mm[tt][ch] = 0.5f*(x0 + x1) - a0s[ch];
        }
        __syncthreads();
        if (act) {
            #pragma unroll
            for (int tt = 0; tt < TCH; ++tt) {
                float4 m0 = *(const float4*)&mm[tt][r0];
                float4 m1 = *(const float4*)&mm[tt][r0+4];
                float4 d0 = *(const float4*)&dd[tt][c0];
                float4 d1 = *(const float4*)&dd[tt][c0+4];
                float mv[8] = {m0.x,m0.y,m0.z,m0.w,m1.x,m1.y,m1.z,m1.w};
                float dv[8] = {d0.x,d0.y,d0.z,d0.w,d1.x,d1.y,d1.z,d1.w};
                #pragma unroll
                for (int rr = 0; rr < 8; ++rr)
                    #pragma unroll
                    for (int cc = 0; cc < 8; ++cc)
                        acc[rr][cc] += mv[rr]*dv[cc];
            }
        }
        __syncthreads();
    }

    float* sn = sig + (long)n*SIGP;
    if (tid < A) sn[tid] = s1s[tid];
    if (tid < 2) sn[SIG_CH + tid] = 0.f;   // zero alignment pads
    if (act) {
        if (r == c) {
            #pragma unroll
            for (int rr = 0; rr < 8; ++rr) {
                int i = r0 + rr;
                if (i >= A) continue;
                #pragma unroll
                for (int cc = 0; cc < 8; ++cc) {
                    int j = c0 + cc;
                    if (j < A) sn[A + i*A + j] = acc[rr][cc];
                }
            }
        } else {
            #pragma unroll
            for (int rr = 0; rr < 8; ++rr) {
                int i = r0 + rr;
                if (i >= A) continue;
                #pragma unroll
                for (int cc = 0; cc < 8; ++cc) {
                    int j = c0 + cc;
                    float v = acc[rr][cc];
                    sn[A + i*A + j] = v;
                    sn[A + j*A + i] = s1s[j]*s1s[i] - v;
                }
            }
        }
    }
}

// ---------------------------------------------------------------------------
// Kernel C: split-K GEMM fp32, float4 loads, register-prefetch double buffer.
// grid (2,2,SPLITK), 256 threads, 128x128 tile, 8x8 micro (4+4 halves).
// SPLITK*KC = 136*160 = 21760 covers SIGP=21172 with guards.
// ---------------------------------------------------------------------------
#define GBK 16
#define SPLITK 136
#define KC 160
#define NSTEP (KC/GBK)   // 10

__global__ __launch_bounds__(256) void gemm_kernel(
    const float* __restrict__ sig, const float* __restrict__ W,
    float* __restrict__ part)
{
    __shared__ __align__(16) float As[2][GBK][136];
    __shared__ __align__(16) float Bs[2][GBK][128];

    const int tid = threadIdx.x;
    const int tx = tid & 15, ty = tid >> 4;
    const int o0 = blockIdx.x * 128;
    const int n0 = blockIdx.y * 128;
    const int z  = blockIdx.z;
    const int k0 = z * KC;

    // load thread maps
    const int nnA = tid >> 2, qA = (tid & 3) * 4;         // +p*256: nnA+64
    const int kkB = tid >> 5, oqB = (tid & 31) * 4;       // +p*256: kkB+8

    float4 ra[2], rb[2];
    const float4 z4 = {0.f, 0.f, 0.f, 0.f};

    #define LOADSTEP(s)                                                        \
        {                                                                      \
            int kb = k0 + (s)*GBK;                                             \
            _Pragma("unroll")                                                  \
            for (int p = 0; p < 2; ++p) {                                      \
                int ka = kb + qA;                                              \
                ra[p] = (ka < SIGP)                                            \
                    ? *(const float4*)(sig + (long)(n0 + nnA + p*64)*SIGP + ka)\
                    : z4;                                                      \
                int kg = kb + kkB + p*8;                                       \
                rb[p] = (kg < SIG_CH)                                          \
                    ? *(const float4*)(W + (long)kg*OUT + o0 + oqB)            \
                    : z4;                                                      \
            }                                                                  \
        }

    #define STORESTEP(buf)                                                     \
        {                                                                      \
            _Pragma("unroll")                                                  \
            for (int p = 0; p < 2; ++p) {                                      \
                As[buf][qA+0][nnA + p*64] = ra[p].x;                           \
                As[buf][qA+1][nnA + p*64] = ra[p].y;                           \
                As[buf][qA+2][nnA + p*64] = ra[p].z;                           \
                As[buf][qA+3][nnA + p*64] = ra[p].w;                           \
                *(float4*)&Bs[buf][kkB + p*8][oqB] = rb[p];                    \
            }                                                                  \
        }

    float acc[8][8];
    #pragma unroll
    for (int i = 0; i < 8; ++i)
        #pragma unroll
        for (int j = 0; j < 8; ++j) acc[i][j] = 0.f;

    LOADSTEP(0);
    STORESTEP(0);
    __syncthreads();

    for (int s = 0; s < NSTEP; ++s) {
        const int cur = s & 1;
        if (s < NSTEP-1) LOADSTEP(s+1);
        #pragma unroll
        for (int kk = 0; kk < GBK; ++kk) {
            float4 a0 = *(const float4*)&As[cur][kk][ty*4];
            float4 a1 = *(const float4*)&As[cur][kk][64 + ty*4];
            float4 b0 = *(const float4*)&Bs[cur][kk][tx*4];
            float4 b1 = *(const float4*)&Bs[cur][kk][64 + tx*4];
            float av[8] = {a0.x,a0.y,a0.z,a0.w,a1.x,a1.y,a1.z,a1.w};
            float bv[8] = {b0.x,b0.y,b0.z,b0.w,b1.x,b1.y,b1.z,b1.w};
            #pragma unroll
            for (int rr = 0; rr < 8; ++rr)
                #pragma unroll
                for (int cc = 0; cc < 8; ++cc)
                    acc[rr][cc] += av[rr]*bv[cc];
        }
        if (s < NSTEP-1) STORESTEP(cur ^ 1);
        __syncthreads();
    }

    float* pz = part + (long)z * (Nn*OUT);
    #pragma unroll
    for (int rh = 0; rh < 2; ++rh)
        #pragma unroll
        for (int rr = 0; rr < 4; ++rr) {
            int row = n0 + rh*64 + ty*4 + rr;
            int ar = rh*4 + rr;
            float4 v0 = {acc[ar][0], acc[ar][1], acc[ar][2], acc[ar][3]};
            float4 v1 = {acc[ar][4], acc[ar][5], acc[ar][6], acc[ar][7]};
            *(float4*)&pz[row*OUT + o0 + tx*4]      = v0;
            *(float4*)&pz[row*OUT + o0 + 64 + tx*4] = v1;
        }
}

// ---------------------------------------------------------------------------
// Kernel D: out[n][o] = lin_b[o] + sum_z part[z][n][o]
// ---------------------------------------------------------------------------
__global__ __launch_bounds__(256) void reduce_kernel(
    const float* __restrict__ part, const float* __restrict__ lb,
    float* __restrict__ out)
{
    int idx = blockIdx.x * 256 + threadIdx.x;
    float s = lb[idx & 255];
    #pragma unroll 8
    for (int z = 0; z < SPLITK; ++z)
        s += part[(long)z * (Nn*OUT) + idx];
    out[idx] = s;
}

// ---------------------------------------------------------------------------
extern "C" void kernel_launch(void* const* d_in, const int* in_sizes, int n_in,
                              void* d_out, int out_size, void* d_ws, size_t ws_size,
                              hipStream_t stream) {
    const float* q  = (const float*)d_in[0];
    const float* w1 = (const float*)d_in[4];
    const float* b1 = (const float*)d_in[5];
    const float* w2 = (const float*)d_in[6];
    const float* b2 = (const float*)d_in[7];
    const float* lw = (const float*)d_in[8];
    const float* lb = (const float*)d_in[9];
    float* out = (float*)d_out;

    // ws: [aug 37.7MB fp32 | later reused as part 35.7MB][sig 21.7MB fp32]
    float* aug  = (float*)d_ws;
    float* part = (float*)d_ws;   // aliases aug (dead after sig_kernel)
    float* sig  = (float*)((char*)d_ws + (size_t)Nn*T*A*sizeof(float));

    aug_kernel<<<Nn, 256, 0, stream>>>(q, w1, b1, w2, b2, aug);
    sig_kernel<<<Nn, 256, 0, stream>>>(aug, sig);
    gemm_kernel<<<dim3(2, 2, SPLITK), 256, 0, stream>>>(sig, lw, part);
    reduce_kernel<<<(Nn*OUT)/256, 256, 0, stream>>>(part, lb, out);
}

// Round 4
// 261.102 us; speedup vs baseline: 2.1357x; 1.2650x over previous
//
#include <hip/hip_runtime.h>
#include <hip/hip_bf16.h>

// Problem constants
#define Bq 32
#define Lq 256
#define Hq 8
#define Eq 16
#define Nn (Bq*Hq)        // 256 sequences
#define T 254             // Lq - 3 + 1
#define A 145             // E + 1 + 128 augmented channels
#define SIG_CH (A + A*A)  // 21170
#define SIGP 21172        // padded row stride (16B-aligned rows)
#define OUT 256

// ---------------------------------------------------------------------------
// Kernel A: conv1(k=3,16->64) -> conv2(k=1,64->128)+ReLU -> aug[n][t][145]
// 4 t-split blocks per sequence: grid (4, 256). 2 blocks/CU.
// ---------------------------------------------------------------------------
__global__ __launch_bounds__(256) void aug_kernel(
    const float* __restrict__ q,
    const float* __restrict__ w1, const float* __restrict__ b1,
    const float* __restrict__ w2, const float* __restrict__ b2,
    float* __restrict__ aug)
{
    __shared__ __align__(16) float w1s[48*64];    // 12KB
    __shared__ __align__(16) float w2s[64*128];   // 32KB
    __shared__ __align__(16) float b1s[64];
    __shared__ __align__(16) float b2s[128];
    __shared__ __align__(16) float xs[68*16];     // rows tb0..tb0+67, 4.35KB
    __shared__ __align__(16) float a1s[32*64];    // 8KB

    const int tid = threadIdx.x;
    const int n = blockIdx.y;
    const int b = n >> 3, h = n & 7;
    const int tb0 = blockIdx.x * 64;

    for (int i = tid; i < 48*64; i += 256) w1s[i] = w1[i];
    for (int i = tid; i < 64*128; i += 256) w2s[i] = w2[i];
    if (tid < 64)  b1s[tid] = b1[tid];
    if (tid < 128) b2s[tid] = b2[tid];
    {
        const float4* q4 = (const float4*)q + ((long)(b*Lq)*Hq + h)*4;
        float4* xs4 = (float4*)xs;
        for (int i = tid; i < 68*4; i += 256) {
            int rr = i >> 2, e4 = i & 3;
            int t = tb0 + rr; if (t > 255) t = 255;
            xs4[rr*4 + e4] = q4[t*32 + e4];
        }
    }
    __syncthreads();

    const float inv253 = 1.0f / 253.0f;

    #pragma unroll
    for (int sub = 0; sub < 2; ++sub) {
        const int t0 = tb0 + sub*32;
        const int l0 = sub*32;
        // ---- conv1
        {
            const int c = (tid & 15) * 4;
            const int tg = tid >> 4;
            float4 bb = *(const float4*)&b1s[c];
            float4 acc0 = bb, acc1 = bb;
            #pragma unroll
            for (int j = 0; j < 48; ++j) {
                const int dt = j >> 4, i = j & 15;
                float4 w = *(const float4*)&w1s[j*64 + c];
                float xa = xs[(l0 + tg + dt)*16 + i];
                float xb = xs[(l0 + tg + 16 + dt)*16 + i];
                acc0.x += xa*w.x; acc0.y += xa*w.y; acc0.z += xa*w.z; acc0.w += xa*w.w;
                acc1.x += xb*w.x; acc1.y += xb*w.y; acc1.z += xb*w.z; acc1.w += xb*w.w;
            }
            *(float4*)&a1s[tg*64 + c]      = acc0;
            *(float4*)&a1s[(tg+16)*64 + c] = acc1;
        }
        __syncthreads();

        // ---- conv2 + ReLU + store
        {
            const int cq = (tid & 31) * 4;
            const int tg2 = tid >> 5;
            float4 bb = *(const float4*)&b2s[cq];
            float4 acc[4] = {bb, bb, bb, bb};
            #pragma unroll 16
            for (int i = 0; i < 64; ++i) {
                float4 w = *(const float4*)&w2s[i*128 + cq];
                #pragma unroll
                for (int j = 0; j < 4; ++j) {
                    float a = a1s[(tg2 + 8*j)*64 + i];
                    acc[j].x += a*w.x; acc[j].y += a*w.y; acc[j].z += a*w.z; acc[j].w += a*w.w;
                }
            }
            #pragma unroll
            for (int j = 0; j < 4; ++j) {
                int t = t0 + tg2 + 8*j;
                if (t < T) {
                    float* dst = aug + ((long)n*T + t)*A + 17 + cq;
                    dst[0] = fmaxf(acc[j].x, 0.f);
                    dst[1] = fmaxf(acc[j].y, 0.f);
                    dst[2] = fmaxf(acc[j].z, 0.f);
                    dst[3] = fmaxf(acc[j].w, 0.f);
                }
            }
        }

        // ---- channels 0..16
        for (int idx = tid; idx < 17*32; idx += 256) {
            int ch = idx >> 5, tt = idx & 31;
            int t = t0 + tt;
            if (t < T) {
                float val = (ch < 16) ? xs[(l0 + tt + 2)*16 + ch] : (float)t * inv253;
                aug[((long)n*T + t)*A + ch] = val;
            }
        }
        __syncthreads();
    }
}

// ---------------------------------------------------------------------------
// Kernel B: depth-2 signature, 1024 threads/block, 4 t-groups of 256.
// s2[i,j] = sum_t m_t[i]*d_t[j]; lower-triangle 8x8 tiles + Chen mirror.
// Groups accumulate register tiles over their 64-step quarter, then merge
// via transposed LDS accumulator and write out cooperatively.
// ---------------------------------------------------------------------------
#define NTRI 190

__global__ __launch_bounds__(1024) void sig_kernel(
    const float* __restrict__ aug, float* __restrict__ sig)
{
    // smem float layout:
    // [0,5472)      rows: 4 groups x 9x152
    // [5472,10336)  mm:   4 groups x 8x152
    // [10336,15200) dd:   4 groups x 8x152
    // accr aliases [0,12160) after staging is dead: [64 elem][190 tri]
    // [15200,15352) a0s ; [15352,15504) s1s
    __shared__ __align__(16) float smem[15504];

    const int tid = threadIdx.x;
    const int g = tid >> 8, lid = tid & 255;
    const int n = blockIdx.x;
    const float* an = aug + (long)n*T*A;

    float* a0s = smem + 15200;
    float* s1s = smem + 15352;
    if (tid < 152) {
        float a0 = (tid < A) ? an[tid] : 0.f;
        a0s[tid] = a0;
        s1s[tid] = ((tid < A) ? an[(T-1)*A + tid] : 0.f) - a0;
    }

    // triangle tile (r,c), c<=r, for lid < NTRI
    int r = 0, base = 0;
    const bool act = lid < NTRI;
    if (act) { while (base + r + 1 <= lid) { base += r + 1; ++r; } }
    const int c = lid - base;
    const int r0 = r*8, c0 = c*8;

    float* rowsg = smem + g*1368;          // 9x152
    float* mmg   = smem + 5472  + g*1216;  // 8x152
    float* ddg   = smem + 10336 + g*1216;  // 8x152

    float acc[8][8];
    #pragma unroll
    for (int i = 0; i < 8; ++i)
        #pragma unroll
        for (int j = 0; j < 8; ++j) acc[i][j] = 0.f;

    __syncthreads();

    const int tbase = g*64;
    for (int ch = 0; ch < 8; ++ch) {
        const int t0 = tbase + ch*8;
        // stage 9 rows (clamped; clamp => d=0)
        for (int i = lid; i < 9*152; i += 256) {
            int rr = i / 152, cc = i - rr*152;
            int t = t0 + rr; if (t > T-1) t = T-1;
            rowsg[i] = (cc < A) ? an[t*A + cc] : 0.f;
        }
        __syncthreads();
        {
            const float4* r4 = (const float4*)rowsg;
            float4* m4 = (float4*)mmg;
            float4* d4 = (float4*)ddg;
            const float4* a04 = (const float4*)a0s;
            for (int i = lid; i < 8*38; i += 256) {
                int tt = i / 38, c4 = i - tt*38;
                float4 x0 = r4[tt*38 + c4], x1 = r4[(tt+1)*38 + c4];
                float4 av = a04[c4];
                float4 dv, mv;
                dv.x = x1.x - x0.x; dv.y = x1.y - x0.y; dv.z = x1.z - x0.z; dv.w = x1.w - x0.w;
                mv.x = 0.5f*(x0.x + x1.x) - av.x;
                mv.y = 0.5f*(x0.y + x1.y) - av.y;
                mv.z = 0.5f*(x0.z + x1.z) - av.z;
                mv.w = 0.5f*(x0.w + x1.w) - av.w;
                d4[i] = dv; m4[i] = mv;
            }
        }
        __syncthreads();
        if (act) {
            #pragma unroll
            for (int tt = 0; tt < 8; ++tt) {
                float4 m0 = *(const float4*)(mmg + tt*152 + r0);
                float4 m1 = *(const float4*)(mmg + tt*152 + r0 + 4);
                float4 d0 = *(const float4*)(ddg + tt*152 + c0);
                float4 d1 = *(const float4*)(ddg + tt*152 + c0 + 4);
                float mv[8] = {m0.x,m0.y,m0.z,m0.w,m1.x,m1.y,m1.z,m1.w};
                float dv[8] = {d0.x,d0.y,d0.z,d0.w,d1.x,d1.y,d1.z,d1.w};
                #pragma unroll
                for (int rr = 0; rr < 8; ++rr)
                    #pragma unroll
                    for (int cc = 0; cc < 8; ++cc)
                        acc[rr][cc] += mv[rr]*dv[cc];
            }
        }
        __syncthreads();
    }

    // merge groups into accr[e*190 + tri] (stride-1 across lanes: no conflicts)
    float* accr = smem;   // aliases dead staging region, 12160 floats
    for (int gp = 0; gp < 4; ++gp) {
        if (g == gp && act) {
            if (gp == 0) {
                #pragma unroll
                for (int rr = 0; rr < 8; ++rr)
                    #pragma unroll
                    for (int cc = 0; cc < 8; ++cc)
                        accr[(rr*8 + cc)*190 + lid] = acc[rr][cc];
            } else {
                #pragma unroll
                for (int rr = 0; rr < 8; ++rr)
                    #pragma unroll
                    for (int cc = 0; cc < 8; ++cc)
                        accr[(rr*8 + cc)*190 + lid] += acc[rr][cc];
            }
        }
        __syncthreads();
    }

    // cooperative write-out
    float* sn = sig + (long)n*SIGP;
    if (tid < A) sn[tid] = s1s[tid];
    if (tid >= A && tid < A + 2) sn[SIG_CH + (tid - A)] = 0.f;   // row pads
    for (int flat = tid; flat < A*A; flat += 1024) {
        int i = flat / A, j = flat - i*A;
        int rr = i >> 3, cc = j >> 3;
        float v;
        if (cc <= rr) {
            int tri = ((rr*(rr+1)) >> 1) + cc;
            v = accr[((i & 7)*8 + (j & 7))*190 + tri];
        } else {
            int tri = ((cc*(cc+1)) >> 1) + rr;
            v = s1s[i]*s1s[j] - accr[((j & 7)*8 + (i & 7))*190 + tri];
        }
        sn[A + flat] = v;
    }
}

// ---------------------------------------------------------------------------
// Kernel C: split-K GEMM fp32, float4 loads, register-prefetch double buffer.
// grid (2,2,SPLITK), 256 threads, 128x128 tile, 8x8 micro (4+4 halves).
// ---------------------------------------------------------------------------
#define GBK 16
#define SPLITK 136
#define KC 160
#define NSTEP (KC/GBK)   // 10

__global__ __launch_bounds__(256) void gemm_kernel(
    const float* __restrict__ sig, const float* __restrict__ W,
    float* __restrict__ part)
{
    __shared__ __align__(16) float As[2][GBK][136];
    __shared__ __align__(16) float Bs[2][GBK][128];

    const int tid = threadIdx.x;
    const int tx = tid & 15, ty = tid >> 4;
    const int o0 = blockIdx.x * 128;
    const int n0 = blockIdx.y * 128;
    const int z  = blockIdx.z;
    const int k0 = z * KC;

    const int nnA = tid >> 2, qA = (tid & 3) * 4;
    const int kkB = tid >> 5, oqB = (tid & 31) * 4;

    float4 ra[2], rb[2];
    const float4 z4 = {0.f, 0.f, 0.f, 0.f};

    #define LOADSTEP(s)                                                        \
        {                                                                      \
            int kb = k0 + (s)*GBK;                                             \
            _Pragma("unroll")                                                  \
            for (int p = 0; p < 2; ++p) {                                      \
                int ka = kb + qA;                                              \
                ra[p] = (ka < SIGP)                                            \
                    ? *(const float4*)(sig + (long)(n0 + nnA + p*64)*SIGP + ka)\
                    : z4;                                                      \
                int kg = kb + kkB + p*8;                                       \
                rb[p] = (kg < SIG_CH)                                          \
                    ? *(const float4*)(W + (long)kg*OUT + o0 + oqB)            \
                    : z4;                                                      \
            }                                                                  \
        }

    #define STORESTEP(buf)                                                     \
        {                                                                      \
            _Pragma("unroll")                                                  \
            for (int p = 0; p < 2; ++p) {                                      \
                As[buf][qA+0][nnA + p*64] = ra[p].x;                           \
                As[buf][qA+1][nnA + p*64] = ra[p].y;                           \
                As[buf][qA+2][nnA + p*64] = ra[p].z;                           \
                As[buf][qA+3][nnA + p*64] = ra[p].w;                           \
                *(float4*)&Bs[buf][kkB + p*8][oqB] = rb[p];                    \
            }                                                                  \
        }

    float acc[8][8];
    #pragma unroll
    for (int i = 0; i < 8; ++i)
        #pragma unroll
        for (int j = 0; j < 8; ++j) acc[i][j] = 0.f;

    LOADSTEP(0);
    STORESTEP(0);
    __syncthreads();

    for (int s = 0; s < NSTEP; ++s) {
        const int cur = s & 1;
        if (s < NSTEP-1) LOADSTEP(s+1);
        #pragma unroll
        for (int kk = 0; kk < GBK; ++kk) {
            float4 a0 = *(const float4*)&As[cur][kk][ty*4];
            float4 a1 = *(const float4*)&As[cur][kk][64 + ty*4];
            float4 b0 = *(const float4*)&Bs[cur][kk][tx*4];
            float4 b1 = *(const float4*)&Bs[cur][kk][64 + tx*4];
            float av[8] = {a0.x,a0.y,a0.z,a0.w,a1.x,a1.y,a1.z,a1.w};
            float bv[8] = {b0.x,b0.y,b0.z,b0.w,b1.x,b1.y,b1.z,b1.w};
            #pragma unroll
            for (int rr = 0; rr < 8; ++rr)
                #pragma unroll
                for (int cc = 0; cc < 8; ++cc)
                    acc[rr][cc] += av[rr]*bv[cc];
        }
        if (s < NSTEP-1) STORESTEP(cur ^ 1);
        __syncthreads();
    }

    float* pz = part + (long)z * (Nn*OUT);
    #pragma unroll
    for (int rh = 0; rh < 2; ++rh)
        #pragma unroll
        for (int rr = 0; rr < 4; ++rr) {
            int row = n0 + rh*64 + ty*4 + rr;
            int ar = rh*4 + rr;
            float4 v0 = {acc[ar][0], acc[ar][1], acc[ar][2], acc[ar][3]};
            float4 v1 = {acc[ar][4], acc[ar][5], acc[ar][6], acc[ar][7]};
            *(float4*)&pz[row*OUT + o0 + tx*4]      = v0;
            *(float4*)&pz[row*OUT + o0 + 64 + tx*4] = v1;
        }
}

// ---------------------------------------------------------------------------
// Kernel D: out[n][o] = lin_b[o] + sum_z part[z][n][o]
// ---------------------------------------------------------------------------
__global__ __launch_bounds__(256) void reduce_kernel(
    const float* __restrict__ part, const float* __restrict__ lb,
    float* __restrict__ out)
{
    int idx = blockIdx.x * 256 + threadIdx.x;
    float s = lb[idx & 255];
    #pragma unroll 8
    for (int z = 0; z < SPLITK; ++z)
        s += part[(long)z * (Nn*OUT) + idx];
    out[idx] = s;
}

// ---------------------------------------------------------------------------
extern "C" void kernel_launch(void* const* d_in, const int* in_sizes, int n_in,
                              void* d_out, int out_size, void* d_ws, size_t ws_size,
                              hipStream_t stream) {
    const float* q  = (const float*)d_in[0];
    const float* w1 = (const float*)d_in[4];
    const float* b1 = (const float*)d_in[5];
    const float* w2 = (const float*)d_in[6];
    const float* b2 = (const float*)d_in[7];
    const float* lw = (const float*)d_in[8];
    const float* lb = (const float*)d_in[9];
    float* out = (float*)d_out;

    // ws: [aug 37.7MB fp32 | reused as part 35.7MB][sig 21.7MB fp32]
    float* aug  = (float*)d_ws;
    float* part = (float*)d_ws;   // aliases aug (dead after sig_kernel)
    float* sig  = (float*)((char*)d_ws + (size_t)Nn*T*A*sizeof(float));

    aug_kernel<<<dim3(4, Nn), 256, 0, stream>>>(q, w1, b1, w2, b2, aug);
    sig_kernel<<<Nn, 1024, 0, stream>>>(aug, sig);
    gemm_kernel<<<dim3(2, 2, SPLITK), 256, 0, stream>>>(sig, lw, part);
    reduce_kernel<<<(Nn*OUT)/256, 256, 0, stream>>>(part, lb, out);
}

// Round 5
// 211.959 us; speedup vs baseline: 2.6309x; 1.2319x over previous
//
#include <hip/hip_runtime.h>
#include <hip/hip_bf16.h>

// Problem constants
#define Bq 32
#define Lq 256
#define Hq 8
#define Eq 16
#define Nn (Bq*Hq)        // 256 sequences
#define T 254             // Lq - 3 + 1
#define A 145             // E + 1 + 128 augmented channels
#define SIG_CH (A + A*A)  // 21170
#define KP 21184          // padded K (mult of 32), bf16 arrays
#define OUT 256

typedef __attribute__((ext_vector_type(8))) short short8;
typedef __attribute__((ext_vector_type(8))) unsigned short ushort8;
typedef __attribute__((ext_vector_type(4))) float floatx4;

// round-to-nearest-even fp32 -> bf16 bits
static __device__ __forceinline__ unsigned short f2bf(float v) {
    unsigned int u = __float_as_uint(v);
    unsigned int r = (u + 0x7FFFu + ((u >> 16) & 1u)) >> 16;
    return (unsigned short)r;
}
static __device__ __forceinline__ float bf2f(unsigned short b) {
    return __uint_as_float(((unsigned int)b) << 16);
}

// ---------------------------------------------------------------------------
// Kernel A: conv1(k=3,16->64) -> conv2(k=1,64->128)+ReLU -> aug[n][t][145]
// grid (4, 256), 256 threads.
// ---------------------------------------------------------------------------
__global__ __launch_bounds__(256) void aug_kernel(
    const float* __restrict__ q,
    const float* __restrict__ w1, const float* __restrict__ b1,
    const float* __restrict__ w2, const float* __restrict__ b2,
    float* __restrict__ aug)
{
    __shared__ __align__(16) float w1s[48*64];
    __shared__ __align__(16) float w2s[64*128];
    __shared__ __align__(16) float b1s[64];
    __shared__ __align__(16) float b2s[128];
    __shared__ __align__(16) float xs[68*16];
    __shared__ __align__(16) float a1s[32*64];

    const int tid = threadIdx.x;
    const int n = blockIdx.y;
    const int b = n >> 3, h = n & 7;
    const int tb0 = blockIdx.x * 64;

    for (int i = tid; i < 48*64; i += 256) w1s[i] = w1[i];
    for (int i = tid; i < 64*128; i += 256) w2s[i] = w2[i];
    if (tid < 64)  b1s[tid] = b1[tid];
    if (tid < 128) b2s[tid] = b2[tid];
    {
        const float4* q4 = (const float4*)q + ((long)(b*Lq)*Hq + h)*4;
        float4* xs4 = (float4*)xs;
        for (int i = tid; i < 68*4; i += 256) {
            int rr = i >> 2, e4 = i & 3;
            int t = tb0 + rr; if (t > 255) t = 255;
            xs4[rr*4 + e4] = q4[t*32 + e4];
        }
    }
    __syncthreads();

    const float inv253 = 1.0f / 253.0f;

    #pragma unroll
    for (int sub = 0; sub < 2; ++sub) {
        const int t0 = tb0 + sub*32;
        const int l0 = sub*32;
        {
            const int c = (tid & 15) * 4;
            const int tg = tid >> 4;
            float4 bb = *(const float4*)&b1s[c];
            float4 acc0 = bb, acc1 = bb;
            #pragma unroll
            for (int j = 0; j < 48; ++j) {
                const int dt = j >> 4, i = j & 15;
                float4 w = *(const float4*)&w1s[j*64 + c];
                float xa = xs[(l0 + tg + dt)*16 + i];
                float xb = xs[(l0 + tg + 16 + dt)*16 + i];
                acc0.x += xa*w.x; acc0.y += xa*w.y; acc0.z += xa*w.z; acc0.w += xa*w.w;
                acc1.x += xb*w.x; acc1.y += xb*w.y; acc1.z += xb*w.z; acc1.w += xb*w.w;
            }
            *(float4*)&a1s[tg*64 + c]      = acc0;
            *(float4*)&a1s[(tg+16)*64 + c] = acc1;
        }
        __syncthreads();

        {
            const int cq = (tid & 31) * 4;
            const int tg2 = tid >> 5;
            float4 bb = *(const float4*)&b2s[cq];
            float4 acc[4] = {bb, bb, bb, bb};
            #pragma unroll 16
            for (int i = 0; i < 64; ++i) {
                float4 w = *(const float4*)&w2s[i*128 + cq];
                #pragma unroll
                for (int j = 0; j < 4; ++j) {
                    float a = a1s[(tg2 + 8*j)*64 + i];
                    acc[j].x += a*w.x; acc[j].y += a*w.y; acc[j].z += a*w.z; acc[j].w += a*w.w;
                }
            }
            #pragma unroll
            for (int j = 0; j < 4; ++j) {
                int t = t0 + tg2 + 8*j;
                if (t < T) {
                    float* dst = aug + ((long)n*T + t)*A + 17 + cq;
                    dst[0] = fmaxf(acc[j].x, 0.f);
                    dst[1] = fmaxf(acc[j].y, 0.f);
                    dst[2] = fmaxf(acc[j].z, 0.f);
                    dst[3] = fmaxf(acc[j].w, 0.f);
                }
            }
        }

        for (int idx = tid; idx < 17*32; idx += 256) {
            int ch = idx >> 5, tt = idx & 31;
            int t = t0 + tt;
            if (t < T) {
                float val = (ch < 16) ? xs[(l0 + tt + 2)*16 + ch] : (float)t * inv253;
                aug[((long)n*T + t)*A + ch] = val;
            }
        }
        __syncthreads();
    }
}

// ---------------------------------------------------------------------------
// Kernel B: depth-2 signature, 1024 threads, 4 t-groups of 256.
// Epilogue: compensated bf16 split -> sig_hi/sig_lo [n][KP].
// ---------------------------------------------------------------------------
#define NTRI 190

__global__ __launch_bounds__(1024) void sig_kernel(
    const float* __restrict__ aug,
    unsigned short* __restrict__ sig_hi, unsigned short* __restrict__ sig_lo)
{
    __shared__ __align__(16) float smem[15504];

    const int tid = threadIdx.x;
    const int g = tid >> 8, lid = tid & 255;
    const int n = blockIdx.x;
    const float* an = aug + (long)n*T*A;

    float* a0s = smem + 15200;
    float* s1s = smem + 15352;
    if (tid < 152) {
        float a0 = (tid < A) ? an[tid] : 0.f;
        a0s[tid] = a0;
        s1s[tid] = ((tid < A) ? an[(T-1)*A + tid] : 0.f) - a0;
    }

    int r = 0, base = 0;
    const bool act = lid < NTRI;
    if (act) { while (base + r + 1 <= lid) { base += r + 1; ++r; } }
    const int c = lid - base;
    const int r0 = r*8, c0 = c*8;

    float* rowsg = smem + g*1368;
    float* mmg   = smem + 5472  + g*1216;
    float* ddg   = smem + 10336 + g*1216;

    float acc[8][8];
    #pragma unroll
    for (int i = 0; i < 8; ++i)
        #pragma unroll
        for (int j = 0; j < 8; ++j) acc[i][j] = 0.f;

    __syncthreads();

    const int tbase = g*64;
    for (int ch = 0; ch < 8; ++ch) {
        const int t0 = tbase + ch*8;
        for (int i = lid; i < 9*152; i += 256) {
            int rr = i / 152, cc = i - rr*152;
            int t = t0 + rr; if (t > T-1) t = T-1;
            rowsg[i] = (cc < A) ? an[t*A + cc] : 0.f;
        }
        __syncthreads();
        {
            const float4* r4 = (const float4*)rowsg;
            float4* m4 = (float4*)mmg;
            float4* d4 = (float4*)ddg;
            const float4* a04 = (const float4*)a0s;
            for (int i = lid; i < 8*38; i += 256) {
                int tt = i / 38, c4 = i - tt*38;
                float4 x0 = r4[tt*38 + c4], x1 = r4[(tt+1)*38 + c4];
                float4 av = a04[c4];
                float4 dv, mv;
                dv.x = x1.x - x0.x; dv.y = x1.y - x0.y; dv.z = x1.z - x0.z; dv.w = x1.w - x0.w;
                mv.x = 0.5f*(x0.x + x1.x) - av.x;
                mv.y = 0.5f*(x0.y + x1.y) - av.y;
                mv.z = 0.5f*(x0.z + x1.z) - av.z;
                mv.w = 0.5f*(x0.w + x1.w) - av.w;
                d4[i] = dv; m4[i] = mv;
            }
        }
        __syncthreads();
        if (act) {
            #pragma unroll
            for (int tt = 0; tt < 8; ++tt) {
                float4 m0 = *(const float4*)(mmg + tt*152 + r0);
                float4 m1 = *(const float4*)(mmg + tt*152 + r0 + 4);
                float4 d0 = *(const float4*)(ddg + tt*152 + c0);
                float4 d1 = *(const float4*)(ddg + tt*152 + c0 + 4);
                float mv[8] = {m0.x,m0.y,m0.z,m0.w,m1.x,m1.y,m1.z,m1.w};
                float dv[8] = {d0.x,d0.y,d0.z,d0.w,d1.x,d1.y,d1.z,d1.w};
                #pragma unroll
                for (int rr = 0; rr < 8; ++rr)
                    #pragma unroll
                    for (int cc = 0; cc < 8; ++cc)
                        acc[rr][cc] += mv[rr]*dv[cc];
            }
        }
        __syncthreads();
    }

    float* accr = smem;
    for (int gp = 0; gp < 4; ++gp) {
        if (g == gp && act) {
            if (gp == 0) {
                #pragma unroll
                for (int rr = 0; rr < 8; ++rr)
                    #pragma unroll
                    for (int cc = 0; cc < 8; ++cc)
                        accr[(rr*8 + cc)*190 + lid] = acc[rr][cc];
            } else {
                #pragma unroll
                for (int rr = 0; rr < 8; ++rr)
                    #pragma unroll
                    for (int cc = 0; cc < 8; ++cc)
                        accr[(rr*8 + cc)*190 + lid] += acc[rr][cc];
            }
        }
        __syncthreads();
    }

    // write-out: compensated bf16 split
    unsigned short* sh = sig_hi + (long)n*KP;
    unsigned short* sl = sig_lo + (long)n*KP;
    if (tid < A) {
        float v = s1s[tid];
        unsigned short hb = f2bf(v);
        sh[tid] = hb;
        sl[tid] = f2bf(v - bf2f(hb));
    }
    if (tid >= 256 && tid < 256 + (KP - SIG_CH)) {   // zero pads
        sh[SIG_CH + tid - 256] = 0;
        sl[SIG_CH + tid - 256] = 0;
    }
    for (int flat = tid; flat < A*A; flat += 1024) {
        int i = flat / A, j = flat - i*A;
        int rr = i >> 3, cc = j >> 3;
        float v;
        if (cc <= rr) {
            int tri = ((rr*(rr+1)) >> 1) + cc;
            v = accr[((i & 7)*8 + (j & 7))*190 + tri];
        } else {
            int tri = ((cc*(cc+1)) >> 1) + rr;
            v = s1s[i]*s1s[j] - accr[((j & 7)*8 + (i & 7))*190 + tri];
        }
        unsigned short hb = f2bf(v);
        sh[A + flat] = hb;
        sl[A + flat] = f2bf(v - bf2f(hb));
    }
}

// ---------------------------------------------------------------------------
// Kernel W: W[k][o] fp32 -> Wt_hi/Wt_lo[o][KP] bf16 (transposed, split).
// grid (331, 4), 256 threads; 64k x 64o tile via LDS transpose.
// ---------------------------------------------------------------------------
__global__ __launch_bounds__(256) void wconv_kernel(
    const float* __restrict__ W,
    unsigned short* __restrict__ wt_hi, unsigned short* __restrict__ wt_lo)
{
    __shared__ float ls[64][65];
    const int tid = threadIdx.x;
    const int k0 = blockIdx.x * 64;
    const int o0 = blockIdx.y * 64;

    #pragma unroll
    for (int p = 0; p < 16; ++p) {
        int idx = tid + p*256;
        int kk = idx >> 6, oo = idx & 63;
        int k = k0 + kk;
        ls[kk][oo] = (k < SIG_CH) ? W[(long)k*OUT + o0 + oo] : 0.f;
    }
    __syncthreads();

    const int oo = tid >> 2;
    const int kq = (tid & 3) * 16;
    unsigned short hbuf[16], lbuf[16];
    #pragma unroll
    for (int j = 0; j < 16; ++j) {
        float v = ls[kq + j][oo];
        unsigned short hb = f2bf(v);
        hbuf[j] = hb;
        lbuf[j] = f2bf(v - bf2f(hb));
    }
    long off = (long)(o0 + oo)*KP + k0 + kq;
    *(ushort8*)(wt_hi + off)     = *(ushort8*)&hbuf[0];
    *(ushort8*)(wt_hi + off + 8) = *(ushort8*)&hbuf[8];
    *(ushort8*)(wt_lo + off)     = *(ushort8*)&lbuf[0];
    *(ushort8*)(wt_lo + off + 8) = *(ushort8*)&lbuf[8];
}

// ---------------------------------------------------------------------------
// Kernel C: MFMA bf16 split GEMM. part[z] += sig * Wt^T over K-chunk.
// grid (2 o, 2 n, 61 z), 256 thr = 4 waves (2x2), wave tile 64x64 =
// 4x4 mfma_f32_16x16x32_bf16 tiles. 3 products: hi*hi + hi*lo + lo*hi.
// chunk = 352 k = 11 steps of 32.
// ---------------------------------------------------------------------------
#define SPLITK 61
#define KC 352
#define NSTEP (KC/32)   // 11
#define LDA 40          // LDS row stride (bf16 elems)

__global__ __launch_bounds__(256) void gemm_kernel(
    const unsigned short* __restrict__ sig_hi, const unsigned short* __restrict__ sig_lo,
    const unsigned short* __restrict__ wt_hi,  const unsigned short* __restrict__ wt_lo,
    float* __restrict__ part)
{
    __shared__ __align__(16) unsigned short Ah[128*LDA];
    __shared__ __align__(16) unsigned short Al[128*LDA];
    __shared__ __align__(16) unsigned short Bh[128*LDA];
    __shared__ __align__(16) unsigned short Bl[128*LDA];

    const int tid = threadIdx.x;
    const int o0 = blockIdx.x * 128;
    const int n0 = blockIdx.y * 128;
    const int z  = blockIdx.z;
    const int k0 = z * KC;

    const int lane = tid & 63;
    const int w    = tid >> 6;
    const int wm   = w & 1;          // m half
    const int wn   = w >> 1;         // n half
    const int frow = lane & 15;
    const int quad = lane >> 4;

    // staging map: row = tid>>1 (0..127), kh = (tid&1)*16
    const int srow = tid >> 1;
    const int kh   = (tid & 1) * 16;

    const unsigned short* gAh = sig_hi + (long)(n0 + srow)*KP;
    const unsigned short* gAl = sig_lo + (long)(n0 + srow)*KP;
    const unsigned short* gBh = wt_hi  + (long)(o0 + srow)*KP;
    const unsigned short* gBl = wt_lo  + (long)(o0 + srow)*KP;

    ushort8 rah[2], ral[2], rbh[2], rbl[2];
    const ushort8 z8 = {0,0,0,0,0,0,0,0};

    #define GLOAD(s)                                                          \
        {                                                                     \
            int kb = k0 + (s)*32 + kh;                                        \
            if (kb < KP) {                                                    \
                rah[0] = *(const ushort8*)(gAh + kb);                         \
                rah[1] = *(const ushort8*)(gAh + kb + 8);                     \
                ral[0] = *(const ushort8*)(gAl + kb);                         \
                ral[1] = *(const ushort8*)(gAl + kb + 8);                     \
                rbh[0] = *(const ushort8*)(gBh + kb);                         \
                rbh[1] = *(const ushort8*)(gBh + kb + 8);                     \
                rbl[0] = *(const ushort8*)(gBl + kb);                         \
                rbl[1] = *(const ushort8*)(gBl + kb + 8);                     \
            } else {                                                          \
                rah[0]=z8; rah[1]=z8; ral[0]=z8; ral[1]=z8;                   \
                rbh[0]=z8; rbh[1]=z8; rbl[0]=z8; rbl[1]=z8;                   \
            }                                                                 \
        }

    #define LSTORE()                                                          \
        {                                                                     \
            int o = srow*LDA + kh;                                            \
            *(ushort8*)(Ah + o)     = rah[0];                                 \
            *(ushort8*)(Ah + o + 8) = rah[1];                                 \
            *(ushort8*)(Al + o)     = ral[0];                                 \
            *(ushort8*)(Al + o + 8) = ral[1];                                 \
            *(ushort8*)(Bh + o)     = rbh[0];                                 \
            *(ushort8*)(Bh + o + 8) = rbh[1];                                 \
            *(ushort8*)(Bl + o)     = rbl[0];                                 \
            *(ushort8*)(Bl + o + 8) = rbl[1];                                 \
        }

    floatx4 acc[4][4];
    #pragma unroll
    for (int i = 0; i < 4; ++i)
        #pragma unroll
        for (int j = 0; j < 4; ++j)
            acc[i][j] = (floatx4){0.f, 0.f, 0.f, 0.f};

    GLOAD(0);
    LSTORE();
    __syncthreads();

    for (int s = 0; s < NSTEP; ++s) {
        if (s < NSTEP-1) GLOAD(s+1);

        short8 afh[4], afl[4], bfh[4], bfl[4];
        const int aoff = (wm*64 + frow)*LDA + quad*8;
        const int boff = (wn*64 + frow)*LDA + quad*8;
        #pragma unroll
        for (int tI = 0; tI < 4; ++tI) {
            afh[tI] = *(const short8*)(Ah + aoff + tI*16*LDA);
            afl[tI] = *(const short8*)(Al + aoff + tI*16*LDA);
            bfh[tI] = *(const short8*)(Bh + boff + tI*16*LDA);
            bfl[tI] = *(const short8*)(Bl + boff + tI*16*LDA);
        }
        #pragma unroll
        for (int mt = 0; mt < 4; ++mt)
            #pragma unroll
            for (int nt = 0; nt < 4; ++nt) {
                acc[mt][nt] = __builtin_amdgcn_mfma_f32_16x16x32_bf16(
                    afh[mt], bfh[nt], acc[mt][nt], 0, 0, 0);
                acc[mt][nt] = __builtin_amdgcn_mfma_f32_16x16x32_bf16(
                    afh[mt], bfl[nt], acc[mt][nt], 0, 0, 0);
                acc[mt][nt] = __builtin_amdgcn_mfma_f32_16x16x32_bf16(
                    afl[mt], bfh[nt], acc[mt][nt], 0, 0, 0);
            }
        __syncthreads();
        if (s < NSTEP-1) {
            LSTORE();
            __syncthreads();
        }
    }

    // epilogue: C/D layout col=lane&15, row=quad*4+reg
    float* pz = part + (long)z * (Nn*OUT);
    #pragma unroll
    for (int mt = 0; mt < 4; ++mt)
        #pragma unroll
        for (int nt = 0; nt < 4; ++nt) {
            int col = o0 + wn*64 + nt*16 + frow;
            int rbase = n0 + wm*64 + mt*16 + quad*4;
            #pragma unroll
            for (int e = 0; e < 4; ++e)
                pz[(long)(rbase + e)*OUT + col] = acc[mt][nt][e];
        }
}

// ---------------------------------------------------------------------------
// Kernel D: out[n][o] = lin_b[o] + sum_z part[z][n][o]
// ---------------------------------------------------------------------------
__global__ __launch_bounds__(256) void reduce_kernel(
    const float* __restrict__ part, const float* __restrict__ lb,
    float* __restrict__ out)
{
    int idx = blockIdx.x * 256 + threadIdx.x;
    float s = lb[idx & 255];
    #pragma unroll 8
    for (int z = 0; z < SPLITK; ++z)
        s += part[(long)z * (Nn*OUT) + idx];
    out[idx] = s;
}

// ---------------------------------------------------------------------------
extern "C" void kernel_launch(void* const* d_in, const int* in_sizes, int n_in,
                              void* d_out, int out_size, void* d_ws, size_t ws_size,
                              hipStream_t stream) {
    const float* q  = (const float*)d_in[0];
    const float* w1 = (const float*)d_in[4];
    const float* b1 = (const float*)d_in[5];
    const float* w2 = (const float*)d_in[6];
    const float* b2 = (const float*)d_in[7];
    const float* lw = (const float*)d_in[8];
    const float* lb = (const float*)d_in[9];
    float* out = (float*)d_out;

    // ws layout (peak 59.4 MB):
    //   [0]          sig_hi  (256*KP*2 = 10,846,208)
    //   [10846208]   sig_lo  (10,846,208)
    //   [21692416]   aug fp32 (37,713,920)  -- dead after sig_kernel, then:
    //     [21692416] wt_hi (10,846,208)
    //     [32538624] wt_lo (10,846,208)
    //     [43384832] part  (61*65536*4 = 15,990,784)
    char* ws = (char*)d_ws;
    unsigned short* sig_hi = (unsigned short*)ws;
    unsigned short* sig_lo = (unsigned short*)(ws + 10846208);
    float*          aug    = (float*)(ws + 21692416);
    unsigned short* wt_hi  = (unsigned short*)(ws + 21692416);
    unsigned short* wt_lo  = (unsigned short*)(ws + 32538624);
    float*          part   = (float*)(ws + 43384832);

    aug_kernel<<<dim3(4, Nn), 256, 0, stream>>>(q, w1, b1, w2, b2, aug);
    sig_kernel<<<Nn, 1024, 0, stream>>>(aug, sig_hi, sig_lo);
    wconv_kernel<<<dim3(KP/64, OUT/64), 256, 0, stream>>>(lw, wt_hi, wt_lo);
    gemm_kernel<<<dim3(2, 2, SPLITK), 256, 0, stream>>>(sig_hi, sig_lo, wt_hi, wt_lo, part);
    reduce_kernel<<<(Nn*OUT)/256, 256, 0, stream>>>(part, lb, out);
}

// Round 6
// 202.079 us; speedup vs baseline: 2.7595x; 1.0489x over previous
//
#include <hip/hip_runtime.h>
#include <hip/hip_bf16.h>

// Problem constants
#define Bq 32
#define Lq 256
#define Hq 8
#define Eq 16
#define Nn (Bq*Hq)        // 256 sequences
#define T 254             // Lq - 3 + 1
#define A 145             // E + 1 + 128 augmented channels
#define SIG_CH (A + A*A)  // 21170
#define KP 21184          // padded K (mult of 32), bf16 arrays
#define OUT 256
#define TPAD 256          // aug_t row stride (t dimension)

typedef __attribute__((ext_vector_type(8))) short short8;
typedef __attribute__((ext_vector_type(8))) unsigned short ushort8;
typedef __attribute__((ext_vector_type(4))) float floatx4;

static __device__ __forceinline__ unsigned short f2bf(float v) {
    unsigned int u = __float_as_uint(v);
    unsigned int r = (u + 0x7FFFu + ((u >> 16) & 1u)) >> 16;
    return (unsigned short)r;
}
static __device__ __forceinline__ float bf2f(unsigned short b) {
    return __uint_as_float(((unsigned int)b) << 16);
}

// ---------------------------------------------------------------------------
// Kernel A: conv1(k=3,16->64) -> conv2(k=1,64->128)+ReLU.
// Output TRANSPOSED: aug_t[n][ch][t], t contiguous (TPAD=256).
// grid (4, 256), 256 threads.
// ---------------------------------------------------------------------------
__global__ __launch_bounds__(256) void aug_kernel(
    const float* __restrict__ q,
    const float* __restrict__ w1, const float* __restrict__ b1,
    const float* __restrict__ w2, const float* __restrict__ b2,
    float* __restrict__ aug_t)
{
    __shared__ __align__(16) float w1s[48*64];
    __shared__ __align__(16) float w2s[64*128];
    __shared__ __align__(16) float b1s[64];
    __shared__ __align__(16) float b2s[128];
    __shared__ __align__(16) float xs[68*16];
    __shared__ __align__(16) float a1s[32*64];

    const int tid = threadIdx.x;
    const int n = blockIdx.y;
    const int b = n >> 3, h = n & 7;
    const int tb0 = blockIdx.x * 64;

    for (int i = tid; i < 48*64; i += 256) w1s[i] = w1[i];
    for (int i = tid; i < 64*128; i += 256) w2s[i] = w2[i];
    if (tid < 64)  b1s[tid] = b1[tid];
    if (tid < 128) b2s[tid] = b2[tid];
    {
        const float4* q4 = (const float4*)q + ((long)(b*Lq)*Hq + h)*4;
        float4* xs4 = (float4*)xs;
        for (int i = tid; i < 68*4; i += 256) {
            int rr = i >> 2, e4 = i & 3;
            int t = tb0 + rr; if (t > 255) t = 255;
            xs4[rr*4 + e4] = q4[t*32 + e4];
        }
    }
    __syncthreads();

    const float inv253 = 1.0f / 253.0f;

    #pragma unroll
    for (int sub = 0; sub < 2; ++sub) {
        const int t0 = tb0 + sub*32;
        const int l0 = sub*32;
        // conv1
        {
            const int c = (tid & 15) * 4;
            const int tg = tid >> 4;
            float4 bb = *(const float4*)&b1s[c];
            float4 acc0 = bb, acc1 = bb;
            #pragma unroll
            for (int j = 0; j < 48; ++j) {
                const int dt = j >> 4, i = j & 15;
                float4 w = *(const float4*)&w1s[j*64 + c];
                float xa = xs[(l0 + tg + dt)*16 + i];
                float xb = xs[(l0 + tg + 16 + dt)*16 + i];
                acc0.x += xa*w.x; acc0.y += xa*w.y; acc0.z += xa*w.z; acc0.w += xa*w.w;
                acc1.x += xb*w.x; acc1.y += xb*w.y; acc1.z += xb*w.z; acc1.w += xb*w.w;
            }
            *(float4*)&a1s[tg*64 + c]      = acc0;
            *(float4*)&a1s[(tg+16)*64 + c] = acc1;
        }
        __syncthreads();

        // conv2 + ReLU + transposed store
        {
            const int cq = (tid & 31) * 4;
            const int tg2 = tid >> 5;
            float4 bb = *(const float4*)&b2s[cq];
            float4 acc[4] = {bb, bb, bb, bb};
            #pragma unroll 16
            for (int i = 0; i < 64; ++i) {
                float4 w = *(const float4*)&w2s[i*128 + cq];
                #pragma unroll
                for (int j = 0; j < 4; ++j) {
                    float a = a1s[(tg2 + 8*j)*64 + i];
                    acc[j].x += a*w.x; acc[j].y += a*w.y; acc[j].z += a*w.z; acc[j].w += a*w.w;
                }
            }
            const long rb = ((long)n*A + 17 + cq)*TPAD;
            #pragma unroll
            for (int j = 0; j < 4; ++j) {
                int t = t0 + tg2 + 8*j;
                if (t < T) {
                    aug_t[rb + 0*TPAD + t] = fmaxf(acc[j].x, 0.f);
                    aug_t[rb + 1*TPAD + t] = fmaxf(acc[j].y, 0.f);
                    aug_t[rb + 2*TPAD + t] = fmaxf(acc[j].z, 0.f);
                    aug_t[rb + 3*TPAD + t] = fmaxf(acc[j].w, 0.f);
                }
            }
        }

        // channels 0..16 (trunc x + time), transposed store (t coalesced)
        for (int idx = tid; idx < 17*32; idx += 256) {
            int ch = idx >> 5, tt = idx & 31;
            int t = t0 + tt;
            if (t < T) {
                float val = (ch < 16) ? xs[(l0 + tt + 2)*16 + ch] : (float)t * inv253;
                aug_t[((long)n*A + ch)*TPAD + t] = val;
            }
        }
        __syncthreads();
    }
}

// ---------------------------------------------------------------------------
// Kernel B: depth-2 signature via MFMA bf16-split GEMM.
// s2[i][j] = sum_t m_t[i]*d_t[j]  ==  C = Mbar^T(145xK) . D(Kx145), K=253.
// One block per n, 256 thr = 4 waves (2x2 of 80x80), 10x10 16x16 tiles.
// M/D staged per 32-K chunk as bf16 hi/lo in LDS, [ch][t] K-contiguous.
// Epilogue: compensated bf16 split -> sig_hi/sig_lo[n][KP].
// ---------------------------------------------------------------------------
#define CHT 160
#define LDA2 40

__global__ __launch_bounds__(256) void sig_kernel(
    const float* __restrict__ aug_t,
    unsigned short* __restrict__ sig_hi, unsigned short* __restrict__ sig_lo)
{
    __shared__ __align__(16) unsigned short MhT[CHT*LDA2];
    __shared__ __align__(16) unsigned short MlT[CHT*LDA2];
    __shared__ __align__(16) unsigned short DhT[CHT*LDA2];
    __shared__ __align__(16) unsigned short DlT[CHT*LDA2];

    const int tid = threadIdx.x;
    const int n = blockIdx.x;
    const float* an = aug_t + (long)n*A*TPAD;

    const int lane = tid & 63;
    const int w    = tid >> 6;
    const int wm   = w & 1;
    const int wn   = w >> 1;
    const int frow = lane & 15;
    const int quad = lane >> 4;

    const int ch = tid;   // staging row for tid < CHT
    float a0 = 0.f;
    if (ch < A) a0 = an[ch*TPAD];

    floatx4 acc[5][5];
    #pragma unroll
    for (int i = 0; i < 5; ++i)
        #pragma unroll
        for (int j = 0; j < 5; ++j)
            acc[i][j] = (floatx4){0.f, 0.f, 0.f, 0.f};

    for (int c = 0; c < 8; ++c) {
        const int t0 = c*32;
        if (ch < CHT) {
            unsigned int mhp[8], mlp[8], dhp[8], dlp[8];
            if (ch < A) {
                float v[33];
                const float* src = an + ch*TPAD + t0;
                #pragma unroll
                for (int i = 0; i < 8; ++i)
                    *(float4*)&v[i*4] = *(const float4*)(src + i*4);
                v[32] = (t0 + 32 <= 253) ? src[32] : 0.f;
                #pragma unroll
                for (int p = 0; p < 8; ++p) {
                    unsigned int mh = 0, ml = 0, dh = 0, dl = 0;
                    #pragma unroll
                    for (int e = 0; e < 2; ++e) {
                        int tl = p*2 + e*0;  // placeholder
                        tl = p*2 + e;
                        // pack 2 t per uint -> need 4 t per... (2 per uint16x2)
                        bool valid = (t0 + tl*2 + 0) <= 252;  // recomputed below
                        (void)valid;
                    }
                    // straightforward: 4 t-values per pair of uints handled below
                    mhp[p] = 0; mlp[p] = 0; dhp[p] = 0; dlp[p] = 0;
                }
                // compute 32 t-values, pack pairs into uints
                #pragma unroll
                for (int tl2 = 0; tl2 < 16; ++tl2) {
                    int tla = tl2*2, tlb = tl2*2 + 1;
                    bool va = (t0 + tla) <= 252;
                    bool vb = (t0 + tlb) <= 252;
                    float x0a = v[tla], x1a = v[tla+1];
                    float x0b = v[tlb], x1b = v[tlb+1];
                    float da = va ? (x1a - x0a) : 0.f;
                    float ma = va ? (0.5f*(x0a + x1a) - a0) : 0.f;
                    float db = vb ? (x1b - x0b) : 0.f;
                    float mb = vb ? (0.5f*(x0b + x1b) - a0) : 0.f;
                    unsigned short mha = f2bf(ma), mhb2 = f2bf(mb);
                    unsigned short mla = f2bf(ma - bf2f(mha)), mlb = f2bf(mb - bf2f(mhb2));
                    unsigned short dha = f2bf(da), dhb2 = f2bf(db);
                    unsigned short dla = f2bf(da - bf2f(dha)), dlb = f2bf(db - bf2f(dhb2));
                    mhp[tl2 >> 1] = (tl2 & 1)
                        ? (mhp[tl2 >> 1] | ((unsigned int)mha << 0) * 0)  // unreachable pattern
                        : mhp[tl2 >> 1];
                    // simple even/odd packing:
                    if ((tl2 & 1) == 0) {
                        mhp[tl2 >> 1] = (unsigned int)mha | ((unsigned int)mhb2 << 16);
                        mlp[tl2 >> 1] = (unsigned int)mla | ((unsigned int)mlb << 16);
                        dhp[tl2 >> 1] = (unsigned int)dha | ((unsigned int)dhb2 << 16);
                        dlp[tl2 >> 1] = (unsigned int)dla | ((unsigned int)dlb << 16);
                    } else {
                        // second pair of the uint2 group goes to the next slot
                        mhp[(tl2 >> 1) + 0] = mhp[(tl2 >> 1)];  // no-op
                    }
                    // NOTE: mapping fixed below by using tl2 directly as slot of 2-t packs
                }
                // Recompute cleanly: 16 packs of 2 consecutive t each -> 8 uint pairs
                // (The loop above already wrote pack tl2 when (tl2&1)==0 covering t=4*tl2.. hmm)
            }
            // ---- clean scalar fallback pack (correctness-first, still vectorized stores)
            {
                unsigned short mh[32], ml[32], dh[32], dl[32];
                if (ch < A) {
                    float v[33];
                    const float* src = an + ch*TPAD + t0;
                    #pragma unroll
                    for (int i = 0; i < 8; ++i)
                        *(float4*)&v[i*4] = *(const float4*)(src + i*4);
                    v[32] = (t0 + 32 <= 253) ? src[32] : 0.f;
                    #pragma unroll
                    for (int tl = 0; tl < 32; ++tl) {
                        bool valid = (t0 + tl) <= 252;
                        float x0 = v[tl], x1 = v[tl+1];
                        float d = valid ? (x1 - x0) : 0.f;
                        float m = valid ? (0.5f*(x0 + x1) - a0) : 0.f;
                        unsigned short hb = f2bf(m);
                        mh[tl] = hb; ml[tl] = f2bf(m - bf2f(hb));
                        unsigned short db2 = f2bf(d);
                        dh[tl] = db2; dl[tl] = f2bf(d - bf2f(db2));
                    }
                } else {
                    #pragma unroll
                    for (int tl = 0; tl < 32; ++tl) { mh[tl]=0; ml[tl]=0; dh[tl]=0; dl[tl]=0; }
                }
                #pragma unroll
                for (int p = 0; p < 4; ++p) {
                    *(ushort8*)&MhT[ch*LDA2 + p*8] = *(ushort8*)&mh[p*8];
                    *(ushort8*)&MlT[ch*LDA2 + p*8] = *(ushort8*)&ml[p*8];
                    *(ushort8*)&DhT[ch*LDA2 + p*8] = *(ushort8*)&dh[p*8];
                    *(ushort8*)&DlT[ch*LDA2 + p*8] = *(ushort8*)&dl[p*8];
                }
            }
        }
        __syncthreads();

        short8 afh[5], afl[5], bfh[5], bfl[5];
        #pragma unroll
        for (int i = 0; i < 5; ++i) {
            int ar = (wm*80 + i*16 + frow)*LDA2 + quad*8;
            int br = (wn*80 + i*16 + frow)*LDA2 + quad*8;
            afh[i] = *(const short8*)&MhT[ar];
            afl[i] = *(const short8*)&MlT[ar];
            bfh[i] = *(const short8*)&DhT[br];
            bfl[i] = *(const short8*)&DlT[br];
        }
        #pragma unroll
        for (int mt = 0; mt < 5; ++mt)
            #pragma unroll
            for (int nt = 0; nt < 5; ++nt) {
                acc[mt][nt] = __builtin_amdgcn_mfma_f32_16x16x32_bf16(
                    afh[mt], bfh[nt], acc[mt][nt], 0, 0, 0);
                acc[mt][nt] = __builtin_amdgcn_mfma_f32_16x16x32_bf16(
                    afh[mt], bfl[nt], acc[mt][nt], 0, 0, 0);
                acc[mt][nt] = __builtin_amdgcn_mfma_f32_16x16x32_bf16(
                    afl[mt], bfh[nt], acc[mt][nt], 0, 0, 0);
            }
        __syncthreads();
    }

    // epilogue
    unsigned short* sh = sig_hi + (long)n*KP;
    unsigned short* sl = sig_lo + (long)n*KP;
    if (tid < A) {
        float v = an[tid*TPAD + 253] - a0;
        unsigned short hb = f2bf(v);
        sh[tid] = hb;
        sl[tid] = f2bf(v - bf2f(hb));
    }
    if (tid >= 160 && tid < 160 + (KP - SIG_CH)) {
        sh[SIG_CH + tid - 160] = 0;
        sl[SIG_CH + tid - 160] = 0;
    }
    #pragma unroll
    for (int mt = 0; mt < 5; ++mt)
        #pragma unroll
        for (int nt = 0; nt < 5; ++nt) {
            int j = wn*80 + nt*16 + frow;
            int ib = wm*80 + mt*16 + quad*4;
            #pragma unroll
            for (int e = 0; e < 4; ++e) {
                int i = ib + e;
                if (i < A && j < A) {
                    float v = acc[mt][nt][e];
                    unsigned short hb = f2bf(v);
                    sh[A + i*A + j] = hb;
                    sl[A + i*A + j] = f2bf(v - bf2f(hb));
                }
            }
        }
}

// ---------------------------------------------------------------------------
// Kernel W: W[k][o] fp32 -> Wt_hi/Wt_lo[o][KP] bf16 (transposed, split).
// ---------------------------------------------------------------------------
__global__ __launch_bounds__(256) void wconv_kernel(
    const float* __restrict__ W,
    unsigned short* __restrict__ wt_hi, unsigned short* __restrict__ wt_lo)
{
    __shared__ float ls[64][65];
    const int tid = threadIdx.x;
    const int k0 = blockIdx.x * 64;
    const int o0 = blockIdx.y * 64;

    #pragma unroll
    for (int p = 0; p < 16; ++p) {
        int idx = tid + p*256;
        int kk = idx >> 6, oo = idx & 63;
        int k = k0 + kk;
        ls[kk][oo] = (k < SIG_CH) ? W[(long)k*OUT + o0 + oo] : 0.f;
    }
    __syncthreads();

    const int oo = tid >> 2;
    const int kq = (tid & 3) * 16;
    unsigned short hbuf[16], lbuf[16];
    #pragma unroll
    for (int j = 0; j < 16; ++j) {
        float v = ls[kq + j][oo];
        unsigned short hb = f2bf(v);
        hbuf[j] = hb;
        lbuf[j] = f2bf(v - bf2f(hb));
    }
    long off = (long)(o0 + oo)*KP + k0 + kq;
    *(ushort8*)(wt_hi + off)     = *(ushort8*)&hbuf[0];
    *(ushort8*)(wt_hi + off + 8) = *(ushort8*)&hbuf[8];
    *(ushort8*)(wt_lo + off)     = *(ushort8*)&lbuf[0];
    *(ushort8*)(wt_lo + off + 8) = *(ushort8*)&lbuf[8];
}

// ---------------------------------------------------------------------------
// Kernel C: MFMA bf16 split GEMM. part[z] = sig * Wt^T over K-chunk.
// ---------------------------------------------------------------------------
#define SPLITK 61
#define KC 352
#define NSTEP (KC/32)   // 11
#define LDA 40

__global__ __launch_bounds__(256) void gemm_kernel(
    const unsigned short* __restrict__ sig_hi, const unsigned short* __restrict__ sig_lo,
    const unsigned short* __restrict__ wt_hi,  const unsigned short* __restrict__ wt_lo,
    float* __restrict__ part)
{
    __shared__ __align__(16) unsigned short Ah[128*LDA];
    __shared__ __align__(16) unsigned short Al[128*LDA];
    __shared__ __align__(16) unsigned short Bh[128*LDA];
    __shared__ __align__(16) unsigned short Bl[128*LDA];

    const int tid = threadIdx.x;
    const int o0 = blockIdx.x * 128;
    const int n0 = blockIdx.y * 128;
    const int z  = blockIdx.z;
    const int k0 = z * KC;

    const int lane = tid & 63;
    const int w    = tid >> 6;
    const int wm   = w & 1;
    const int wn   = w >> 1;
    const int frow = lane & 15;
    const int quad = lane >> 4;

    const int srow = tid >> 1;
    const int kh   = (tid & 1) * 16;

    const unsigned short* gAh = sig_hi + (long)(n0 + srow)*KP;
    const unsigned short* gAl = sig_lo + (long)(n0 + srow)*KP;
    const unsigned short* gBh = wt_hi  + (long)(o0 + srow)*KP;
    const unsigned short* gBl = wt_lo  + (long)(o0 + srow)*KP;

    ushort8 rah[2], ral[2], rbh[2], rbl[2];
    const ushort8 z8 = {0,0,0,0,0,0,0,0};

    #define GLOAD(s)                                                          \
        {                                                                     \
            int kb = k0 + (s)*32 + kh;                                        \
            if (kb < KP) {                                                    \
                rah[0] = *(const ushort8*)(gAh + kb);                         \
                rah[1] = *(const ushort8*)(gAh + kb + 8);                     \
                ral[0] = *(const ushort8*)(gAl + kb);                         \
                ral[1] = *(const ushort8*)(gAl + kb + 8);                     \
                rbh[0] = *(const ushort8*)(gBh + kb);                         \
                rbh[1] = *(const ushort8*)(gBh + kb + 8);                     \
                rbl[0] = *(const ushort8*)(gBl + kb);                         \
                rbl[1] = *(const ushort8*)(gBl + kb + 8);                     \
            } else {                                                          \
                rah[0]=z8; rah[1]=z8; ral[0]=z8; ral[1]=z8;                   \
                rbh[0]=z8; rbh[1]=z8; rbl[0]=z8; rbl[1]=z8;                   \
            }                                                                 \
        }

    #define LSTORE()                                                          \
        {                                                                     \
            int o = srow*LDA + kh;                                            \
            *(ushort8*)(Ah + o)     = rah[0];                                 \
            *(ushort8*)(Ah + o + 8) = rah[1];                                 \
            *(ushort8*)(Al + o)     = ral[0];                                 \
            *(ushort8*)(Al + o + 8) = ral[1];                                 \
            *(ushort8*)(Bh + o)     = rbh[0];                                 \
            *(ushort8*)(Bh + o + 8) = rbh[1];                                 \
            *(ushort8*)(Bl + o)     = rbl[0];                                 \
            *(ushort8*)(Bl + o + 8) = rbl[1];                                 \
        }

    floatx4 acc[4][4];
    #pragma unroll
    for (int i = 0; i < 4; ++i)
        #pragma unroll
        for (int j = 0; j < 4; ++j)
            acc[i][j] = (floatx4){0.f, 0.f, 0.f, 0.f};

    GLOAD(0);
    LSTORE();
    __syncthreads();

    for (int s = 0; s < NSTEP; ++s) {
        if (s < NSTEP-1) GLOAD(s+1);

        short8 afh[4], afl[4], bfh[4], bfl[4];
        const int aoff = (wm*64 + frow)*LDA + quad*8;
        const int boff = (wn*64 + frow)*LDA + quad*8;
        #pragma unroll
        for (int tI = 0; tI < 4; ++tI) {
            afh[tI] = *(const short8*)(Ah + aoff + tI*16*LDA);
            afl[tI] = *(const short8*)(Al + aoff + tI*16*LDA);
            bfh[tI] = *(const short8*)(Bh + boff + tI*16*LDA);
            bfl[tI] = *(const short8*)(Bl + boff + tI*16*LDA);
        }
        #pragma unroll
        for (int mt = 0; mt < 4; ++mt)
            #pragma unroll
            for (int nt = 0; nt < 4; ++nt) {
                acc[mt][nt] = __builtin_amdgcn_mfma_f32_16x16x32_bf16(
                    afh[mt], bfh[nt], acc[mt][nt], 0, 0, 0);
                acc[mt][nt] = __builtin_amdgcn_mfma_f32_16x16x32_bf16(
                    afh[mt], bfl[nt], acc[mt][nt], 0, 0, 0);
                acc[mt][nt] = __builtin_amdgcn_mfma_f32_16x16x32_bf16(
                    afl[mt], bfh[nt], acc[mt][nt], 0, 0, 0);
            }
        __syncthreads();
        if (s < NSTEP-1) {
            LSTORE();
            __syncthreads();
        }
    }

    float* pz = part + (long)z * (Nn*OUT);
    #pragma unroll
    for (int mt = 0; mt < 4; ++mt)
        #pragma unroll
        for (int nt = 0; nt < 4; ++nt) {
            int col = o0 + wn*64 + nt*16 + frow;
            int rbase = n0 + wm*64 + mt*16 + quad*4;
            #pragma unroll
            for (int e = 0; e < 4; ++e)
                pz[(long)(rbase + e)*OUT + col] = acc[mt][nt][e];
        }
}

// ---------------------------------------------------------------------------
// Kernel D: out[n][o] = lin_b[o] + sum_z part[z][n][o]
// ---------------------------------------------------------------------------
__global__ __launch_bounds__(256) void reduce_kernel(
    const float* __restrict__ part, const float* __restrict__ lb,
    float* __restrict__ out)
{
    int idx = blockIdx.x * 256 + threadIdx.x;
    float s = lb[idx & 255];
    #pragma unroll 8
    for (int z = 0; z < SPLITK; ++z)
        s += part[(long)z * (Nn*OUT) + idx];
    out[idx] = s;
}

// ---------------------------------------------------------------------------
extern "C" void kernel_launch(void* const* d_in, const int* in_sizes, int n_in,
                              void* d_out, int out_size, void* d_ws, size_t ws_size,
                              hipStream_t stream) {
    const float* q  = (const float*)d_in[0];
    const float* w1 = (const float*)d_in[4];
    const float* b1 = (const float*)d_in[5];
    const float* w2 = (const float*)d_in[6];
    const float* b2 = (const float*)d_in[7];
    const float* lw = (const float*)d_in[8];
    const float* lb = (const float*)d_in[9];
    float* out = (float*)d_out;

    // ws layout (peak 59.71 MB):
    //   [0]          sig_hi  (256*KP*2 = 10,846,208)
    //   [10846208]   sig_lo  (10,846,208)
    //   [21692416]   aug_t fp32 [256][145][256] (38,010,880) -- dead after sig:
    //     [21692416] wt_hi (10,846,208)
    //     [32538624] wt_lo (10,846,208)
    //     [43384832] part  (61*65536*4 = 15,990,784)  (ends 59,375,616)
    char* ws = (char*)d_ws;
    unsigned short* sig_hi = (unsigned short*)ws;
    unsigned short* sig_lo = (unsigned short*)(ws + 10846208);
    float*          aug_t  = (float*)(ws + 21692416);
    unsigned short* wt_hi  = (unsigned short*)(ws + 21692416);
    unsigned short* wt_lo  = (unsigned short*)(ws + 32538624);
    float*          part   = (float*)(ws + 43384832);

    aug_kernel<<<dim3(4, Nn), 256, 0, stream>>>(q, w1, b1, w2, b2, aug_t);
    sig_kernel<<<Nn, 256, 0, stream>>>(aug_t, sig_hi, sig_lo);
    wconv_kernel<<<dim3(KP/64, OUT/64), 256, 0, stream>>>(lw, wt_hi, wt_lo);
    gemm_kernel<<<dim3(2, 2, SPLITK), 256, 0, stream>>>(sig_hi, sig_lo, wt_hi, wt_lo, part);
    reduce_kernel<<<(Nn*OUT)/256, 256, 0, stream>>>(part, lb, out);
}